// Round 8
// baseline (428.611 us; speedup 1.0000x reference)
//
#include <hip/hip_runtime.h>
#include <hip/hip_bf16.h>
#include <math.h>

typedef __hip_bfloat16 bf16;
typedef short bf16x8 __attribute__((ext_vector_type(8)));
typedef float f32x4 __attribute__((ext_vector_type(4)));
typedef unsigned u32x4 __attribute__((ext_vector_type(4)));

#define N_NODES 32768
#define D_DIM 128
#define E_EDG 262144
#define M_MOT 131072
#define NG_G 32
#define F_TOT 832
// P: Q2[0,128) K2[128,256) Q3[256,512) K3[512,768) S_mem[768,832)
// dP: dQ2 dK2 dQ3 dK3 Pm ; -0.125*Km@W_Qm folded into bwd B-frags
// lam2=1 lam3=0.5 lamm=1 b2=b3=bm=1 ; no-max softmax, z as reciprocal
// R14: phaseC P-store via LDS tile. R15: XCD-local fill scatter.
// R16: wide phaseE. R17: k_reduce8 + int4 scan. R18: narrow fused_c.
// R19: __expf/__logf. R20: TV precompute (fused_c FETCH 124->102MB).
// R21: non-temporal streams. phaseE (all full-line stores) shows ZERO write
//      excess; phaseC (full-line P + 917K 8B list writes) shows +51MB =
//      115K list lines x ~7 writebacks -- streaming P/Gb/index traffic
//      cycles the 4MB L2 and evicts partially-filled list lines between
//      their ~8 writes. NT-store P, NT-load fill indices (phaseC); NT-store
//      dP (fused_c/phaseE, protects s2/qkb/tvb partial lines).

__device__ __forceinline__ int pidx(int n){ return ((n & 7) << 12) | (n >> 3); }

__device__ __forceinline__ float wsum64(float v){
#pragma unroll
  for (int o = 32; o > 0; o >>= 1) v += __shfl_xor(v, o, 64);
  return v;
}
__device__ __forceinline__ float hsum32(float v){
#pragma unroll
  for (int o = 16; o > 0; o >>= 1) v += __shfl_xor(v, o, 64);
  return v;
}
__device__ __forceinline__ float hmax32(float v){
#pragma unroll
  for (int o = 16; o > 0; o >>= 1) v = fmaxf(v, __shfl_xor(v, o, 64));
  return v;
}
__device__ __forceinline__ float hsum8(float v){
#pragma unroll
  for (int o = 4; o > 0; o >>= 1) v += __shfl_xor(v, o, 64);
  return v;
}
__device__ __forceinline__ float bflo(unsigned u){ return __uint_as_float(u << 16); }
__device__ __forceinline__ float bfhi(unsigned u){ return __uint_as_float(u & 0xffff0000u); }
__device__ __forceinline__ unsigned packbf(float x, float y){
  bf16 a = __float2bfloat16(x), b = __float2bfloat16(y);
  unsigned short ua = *(unsigned short*)&a, ub = *(unsigned short*)&b;
  return (unsigned)ua | ((unsigned)ub << 16);
}
__device__ __forceinline__ void unpk8(uint4 p, float* f){
  f[0] = bflo(p.x); f[1] = bfhi(p.x); f[2] = bflo(p.y); f[3] = bfhi(p.y);
  f[4] = bflo(p.z); f[5] = bfhi(p.z); f[6] = bflo(p.w); f[7] = bfhi(p.w);
}
__device__ __forceinline__ void nt_store4(void* p, unsigned a, unsigned b, unsigned c, unsigned d){
  u32x4 w; w[0] = a; w[1] = b; w[2] = c; w[3] = d;
  __builtin_nontemporal_store(w, (u32x4*)p);
}

// ================ PHASE A: hist (per-XCD copies) | Wcat/Ttb prep | Mprod ================
__global__ __launch_bounds__(256) void k_phaseA(
    const int* c2, const int* u2, const int* c3, const int* u3, const int* v3,
    const float* wq2, const float* wk2, const float* wq3, const float* wk3,
    const float* wqm, const float* wkm, const float* bmem, const float* Ttau,
    int* cnt, float* Wcat, bf16* Ttb, float* Mprod){
  __shared__ float KmL[64];
  int b = blockIdx.x, t = threadIdx.x;
  if (b < 1024){
    int* base = cnt + (size_t)(b & 7) * 5 * N_NODES;   // per-XCD private copy
    int i = b * 256 + t;
    atomicAdd(&base[pidx(c2[i])], 1);
    atomicAdd(&base[N_NODES + pidx(u2[i])], 1);
    if (i < M_MOT){
      atomicAdd(&base[2 * N_NODES + pidx(c3[i])], 1);
      atomicAdd(&base[3 * N_NODES + pidx(u3[i])], 1);
      atomicAdd(&base[4 * N_NODES + pidx(v3[i])], 1);
    }
  } else if (b < 1440){
    int idx = (b - 1024) * 256 + t;
    if (idx < 768 * D_DIM){
      int f = idx / D_DIM, d = idx - f * D_DIM;
      const float* src; int fr;
      if      (f < 128){ src = wq2; fr = f; }
      else if (f < 256){ src = wk2; fr = f - 128; }
      else if (f < 512){ src = wq3; fr = f - 256; }
      else             { src = wk3; fr = f - 512; }
      Wcat[f * D_DIM + d] = src[fr * D_DIM + d];
    } else {
      int j = idx - 768 * D_DIM; // < 8192
      Ttb[j] = __float2bfloat16(Ttau[j]);
    }
  } else {
    int hk = b - 1440;            // 0..63
    int h = hk >> 5, k = hk & 31;
    if (t < 64){
      const float* wrow = wkm + (size_t)(h * 64 + t) * D_DIM;
      const float* brow = bmem + k * D_DIM;
      float acc = 0.f;
      for (int d = 0; d < D_DIM; d++) acc += wrow[d] * brow[d];
      KmL[t] = acc;
    }
    __syncthreads();
    if (t < 128){
      const float* w = wqm + (size_t)(h * 64) * 128 + t;
      float acc = 0.f;
      for (int z = 0; z < 64; z++) acc += w[z * 128] * KmL[z];
      Mprod[t * 64 + hk] = acc;
    }
  }
}

// ================ REDUCE8: sum 8 hist copies into copy 0 (int4, 160 blocks) ================
__global__ __launch_bounds__(256) void k_reduce8(int* cnt){
  int idx = blockIdx.x * 256 + threadIdx.x;     // over 5*N/4 = 40960 int4s
  int4* base = (int4*)cnt;
  int4 s = base[idx];
#pragma unroll
  for (int rr = 1; rr < 8; rr++){
    int4 v = *(const int4*)(cnt + (size_t)rr * 5 * N_NODES + 4 * (size_t)idx);
    s.x += v.x; s.y += v.y; s.z += v.z; s.w += v.w;
  }
  base[idx] = s;
}

// ================ PHASE B: scan (copy 0, int4) | layernorm | pack_frags ================
__global__ __launch_bounds__(1024) void k_phaseB(
    int* cntcur, int* off,
    const float* X, const float* gamma, const float* beta,
    bf16* Gb, float* mu, float* rstd, float* e_node,
    const float* Wcat, const float* Mprod, bf16* wfF, bf16* wfB){
  __shared__ int sd[1024];
  int b = blockIdx.x, t = threadIdx.x;
  if (b < 5){
    int* c = cntcur + b * N_NODES;
    int* o = off + b * (N_NODES + 1);
    int4 lv[8];
    const int4* c4 = (const int4*)c;
#pragma unroll
    for (int j4 = 0; j4 < 8; j4++) lv[j4] = c4[t * 8 + j4];
    int* lvp = (int*)lv;
    int loc[32];
    int sum = 0;
#pragma unroll
    for (int j = 0; j < 32; j++){ loc[j] = sum; sum += lvp[j]; }
    sd[t] = sum;
    __syncthreads();
    for (int s = 1; s < 1024; s <<= 1){
      int v = (t >= s) ? sd[t - s] : 0;
      __syncthreads();
      sd[t] += v;
      __syncthreads();
    }
    int excl = sd[t] - sum;
#pragma unroll
    for (int j = 0; j < 32; j++){
      int val = excl + loc[j];
      o[t * 32 + j] = val;
      c[t * 32 + j] = val;         // copy 0 becomes "cur" for the fill
    }
    if (t == 1023) o[N_NODES] = sd[1023];
  } else if (b < 2053){
    int wv = t >> 6, l = t & 63;
    int n = (b - 5) * 16 + wv;
    float2 x2 = ((const float2*)(X + (size_t)n * 128))[l];
    float sumx = wsum64(x2.x + x2.y);
    float sumxx = wsum64(x2.x * x2.x + x2.y * x2.y);
    float m = sumx * (1.0f / 128.0f);
    float var = sumxx * (1.0f / 128.0f) - m * m;
    float rs = rsqrtf(var + 1e-5f);
    float2 gg = ((const float2*)gamma)[l];
    float2 bb = ((const float2*)beta)[l];
    ((unsigned*)(Gb + (size_t)n * 128))[l] =
        packbf(gg.x * (x2.x - m) * rs + bb.x, gg.y * (x2.y - m) * rs + bb.y);
    if (l == 0){ mu[n] = m; rstd[n] = rs; e_node[n] = 0.5f * sumxx; }
  } else {
    int idx = (b - 2053) * 1024 + t;   // < 106496
    int j = idx & 7, lane = (idx >> 3) & 63, tt = idx >> 9;
    {
      int tn = tt >> 2, kt = tt & 3;
      int f = tn * 16 + (lane & 15), d = kt * 32 + (lane >> 4) * 8 + j;
      float v = (f < 768) ? Wcat[f * 128 + d] : 0.125f * Mprod[d * 64 + (f - 768)];
      wfF[idx] = __float2bfloat16(v);
    }
    {
      int td = tt / 26, tf = tt - td * 26;
      int f = tf * 32 + (lane >> 4) * 8 + j, d = td * 16 + (lane & 15);
      float v = (f < 768) ? Wcat[f * 128 + d] : -0.125f * Mprod[d * 64 + (f - 768)];
      wfB[idx] = __float2bfloat16(v);
    }
  }
}

// ================ PHASE C: fwd_mfma (13/29) | fill (16/29, residue-owned) ================
__global__ __launch_bounds__(256) void k_phaseC(
    const bf16* Gb, const bf16* wfF, bf16* P,
    const int* c2, const int* u2, const int* c3, const int* u3, const int* v3,
    const int* t3, int* cur,
    uint2* lec, uint2* leu, uint2* lmc, uint2* lmu, uint2* lmv){
  int b = blockIdx.x;
  int g = b / 29, r = b - g * 29;
  if (r < 13){
    // 64x64 output tile, LDS-staged for sector-aligned coalesced NT stores.
    __shared__ unsigned shP[64 * 36];
    int f = g * 13 + r;
    int bx = f & 511, by = f >> 9;
    int wave = threadIdx.x >> 6, lane = threadIdx.x & 63;
    int m0 = bx * 64 + wave * 16;
    int tn0 = by * 4;
    int rw = lane & 15, quad = lane >> 4;
    const bf16* aptr = Gb + (size_t)(m0 + rw) * 128 + quad * 8;
    bf16x8 a[4];
#pragma unroll
    for (int kt = 0; kt < 4; kt++) a[kt] = *(const bf16x8*)(aptr + kt * 32);
    f32x4 acc[4];
#pragma unroll
    for (int i = 0; i < 4; i++) acc[i] = (f32x4){0.f, 0.f, 0.f, 0.f};
#pragma unroll
    for (int nf = 0; nf < 4; nf++){
      int tn = tn0 + nf;
#pragma unroll
      for (int kt = 0; kt < 4; kt++){
        bf16x8 bb = *(const bf16x8*)(wfF + (((size_t)tn * 4 + kt) * 64 + lane) * 8);
        acc[nf] = __builtin_amdgcn_mfma_f32_16x16x32_bf16(bb, a[kt], acc[nf], 0, 0, 0);
      }
    }
    int lrow = wave * 16 + rw;
#pragma unroll
    for (int nf = 0; nf < 4; nf++){
      unsigned lo = packbf(acc[nf][0], acc[nf][1]);
      unsigned hi = packbf(acc[nf][2], acc[nf][3]);
      *(uint2*)&shP[lrow * 36 + nf * 8 + quad * 2] = make_uint2(lo, hi);
    }
    __syncthreads();
    int t = threadIdx.x;
    int orow = t >> 2, s = t & 3;
    u32x4 v0 = *(const u32x4*)&shP[orow * 36 + s * 4];
    u32x4 v1 = *(const u32x4*)&shP[orow * 36 + 16 + s * 4];
    u32x4* prow = (u32x4*)(P + (size_t)(bx * 64 + orow) * F_TOT) + tn0 * 2 + s;
    __builtin_nontemporal_store(v0, prow);
    __builtin_nontemporal_store(v1, prow + 4);
  } else {
    int j = g * 16 + (r - 13);     // 0..8191 ; 8 consecutive blocks per range
    int range = j >> 3;
    int res = b & 7;               // residue ownership == XCD under round-robin
    int i = range * 256 + threadIdx.x;
    {
      int c = __builtin_nontemporal_load(c2 + i);
      int u = __builtin_nontemporal_load(u2 + i);
      if ((c & 7) == res){
        int pos = atomicAdd(&cur[pidx(c)], 1);
        lec[pos] = make_uint2((unsigned)u, (unsigned)i);
      }
      if ((u & 7) == res){
        int pos = atomicAdd(&cur[N_NODES + pidx(u)], 1);
        leu[pos] = make_uint2((unsigned)c, (unsigned)i);
      }
    }
    if (i < M_MOT){
      int c = __builtin_nontemporal_load(c3 + i);
      int u = __builtin_nontemporal_load(u3 + i);
      int v = __builtin_nontemporal_load(v3 + i);
      int mt = __builtin_nontemporal_load(t3 + i);
      if ((c & 7) == res){
        int pos = atomicAdd(&cur[2 * N_NODES + pidx(c)], 1);
        lmc[pos] = make_uint2((unsigned)(u | (v << 16)), (unsigned)(mt | (i << 5)));
      }
      if ((u & 7) == res){
        int pos = atomicAdd(&cur[3 * N_NODES + pidx(u)], 1);
        lmu[pos] = make_uint2((unsigned)c, (unsigned)i);
      }
      if ((v & 7) == res){
        int pos = atomicAdd(&cur[4 * N_NODES + pidx(v)], 1);
        lmv[pos] = make_uint2((unsigned)(c | (mt << 16)), (unsigned)i);
      }
    }
  }
}

// ================ TV precompute: TV4[node][t] = {<T[t,hr,:],K3[node,hr,:]>}_hr0..3 ================
__global__ __launch_bounds__(256) void k_tv(const bf16* P, const bf16* Ttb, float* TV4){
  __shared__ float sh[64 * 132];   // node-major, stride 132 dwords (pad vs 128)
  int blk = blockIdx.x;            // 512 blocks x 64 nodes
  int wave = threadIdx.x >> 6, lane = threadIdx.x & 63;
  int rw = lane & 15, quad = lane >> 4;
  int m0 = blk * 64 + wave * 16;
  const bf16* kbase = P + (size_t)(m0 + rw) * F_TOT + 512 + quad * 8;
#pragma unroll
  for (int hr = 0; hr < 4; hr++){
    bf16x8 a0 = *(const bf16x8*)(kbase + hr * 64);
    bf16x8 a1 = *(const bf16x8*)(kbase + hr * 64 + 32);
    f32x4 acc0 = (f32x4){0.f,0.f,0.f,0.f};
    f32x4 acc1 = (f32x4){0.f,0.f,0.f,0.f};
    {
      const bf16* tb = Ttb + (size_t)rw * 256 + hr * 64 + quad * 8;
      bf16x8 t0 = *(const bf16x8*)(tb);
      bf16x8 t1 = *(const bf16x8*)(tb + 32);
      acc0 = __builtin_amdgcn_mfma_f32_16x16x32_bf16(t0, a0, acc0, 0, 0, 0);
      acc0 = __builtin_amdgcn_mfma_f32_16x16x32_bf16(t1, a1, acc0, 0, 0, 0);
    }
    {
      const bf16* tb = Ttb + (size_t)(16 + rw) * 256 + hr * 64 + quad * 8;
      bf16x8 t0 = *(const bf16x8*)(tb);
      bf16x8 t1 = *(const bf16x8*)(tb + 32);
      acc1 = __builtin_amdgcn_mfma_f32_16x16x32_bf16(t0, a0, acc1, 0, 0, 0);
      acc1 = __builtin_amdgcn_mfma_f32_16x16x32_bf16(t1, a1, acc1, 0, 0, 0);
    }
    int lrow = wave * 16 + rw;
#pragma unroll
    for (int r_ = 0; r_ < 4; r_++){
      sh[lrow * 132 + (quad * 4 + r_) * 4 + hr] = acc0[r_];
      sh[lrow * 132 + (16 + quad * 4 + r_) * 4 + hr] = acc1[r_];
    }
  }
  __syncthreads();
  int t = threadIdx.x;
#pragma unroll
  for (int it = 0; it < 8; it++){
    int idx4 = it * 256 + t;             // [0, 2048): node*32 + t
    int node = idx4 >> 5, toff = (idx4 & 31) * 4;
    float4 v = *(const float4*)&sh[node * 132 + toff];
    ((float4*)TV4)[(size_t)blk * 2048 + idx4] = v;
  }
}

// ================ PHASE D: fused forward gathers (narrow; TV table for tv) ================
__global__ __launch_bounds__(256) void k_fused_c(const bf16* P, const uint2* lec, const uint2* lmc,
                   const bf16* Ttb, const float* TV4, const float* a2,
                   const int* off_ec, const int* off_mc,
                   float* s2, float* rz2, float* s3, float* qkb, float* tvb, float* rz3,
                   bf16* dP, float* e_pair, float* e_mot, float* e_mem){
  int b = blockIdx.x;
  int type = b % 3, grp = b / 3;
  int wave = threadIdx.x >> 6, z = threadIdx.x & 63;
  int n = grp * 4 + wave;
  int l = z & 31, lh = z >> 5;
  int pn = pidx(n);

  if (type == 0){
    // ---- edges: 4 per wave (16-lane groups), 8-lane head sub-groups ----
    int q = z >> 4, l16 = z & 15, hg = l16 >> 3;
    int beg = off_ec[pn], end = off_ec[pn + 1];
    uint4 qp = ((const uint4*)(P + (size_t)n * F_TOT))[l16];
    float qv[8]; unpk8(qp, qv);
    float acc[8] = {0,0,0,0,0,0,0,0};
    float zz = 0.f;
    int iters = (end - beg + 3) >> 2;
    for (int it = 0; it < iters; it++){
      int idx = beg + 4 * it + q;
      bool valid = idx < end;
      int idc = valid ? idx : end - 1;
      uint2 pl = lec[idc];               // (u, eid)
      float2 av = *(const float2*)(a2 + (size_t)pl.y * 2);
      uint4 kp = ((const uint4*)(P + (size_t)pl.x * F_TOT + 128))[l16];
      float kv[8]; unpk8(kp, kv);
      float d = 0.f;
#pragma unroll
      for (int j = 0; j < 8; j++) d += qv[j] * kv[j];
      float s = hsum8(d) * 0.125f + (hg ? av.y : av.x);
      if (valid && (l16 & 7) == 0) s2[2 * pl.y + hg] = s;
      float ex = valid ? __expf(s) : 0.f;
#pragma unroll
      for (int j = 0; j < 8; j++) acc[j] += ex * kv[j];
      zz += ex;
    }
#pragma unroll
    for (int j = 0; j < 8; j++){
      acc[j] += __shfl_xor(acc[j], 16, 64);
      acc[j] += __shfl_xor(acc[j], 32, 64);
    }
    zz += __shfl_xor(zz, 16, 64);
    zz += __shfl_xor(zz, 32, 64);
    float rz = (zz > 0.f) ? 1.0f / zz : 0.f;
    float coef = -0.125f * rz;
    if (z < 16){
      nt_store4((uint4*)(dP + (size_t)n * F_TOT) + l16,
                packbf(coef * acc[0], coef * acc[1]),
                packbf(coef * acc[2], coef * acc[3]),
                packbf(coef * acc[4], coef * acc[5]),
                packbf(coef * acc[6], coef * acc[7]));
      if ((l16 & 7) == 0) rz2[n * 2 + hg] = rz;
    }
    float eterm = (zz > 0.f) ? -__logf(zz) : 0.f;   // lam2 = 1
    float eo = __shfl(eterm, 8, 64);
    if (z == 0) e_pair[n] = eterm + eo;
  } else if (type == 1){
    // ---- motifs: 2 per wave (32-lane halves), 8-lane hr groups; tv from TV4 ----
    int g = l >> 3, hg = g >> 1;
    int beg = off_mc[pn], end = off_mc[pn + 1];
    uint4 qp = ((const uint4*)(P + (size_t)n * F_TOT + 256))[l];
    float qv[8]; unpk8(qp, qv);
    float acc[8] = {0,0,0,0,0,0,0,0};
    float zz = 0.f;
    int iters = (end - beg + 1) >> 1;
    for (int it = 0; it < iters; it++){
      int idx = beg + 2 * it + lh;
      bool valid = idx < end;
      int idc = valid ? idx : end - 1;
      uint2 pl = lmc[idc];               // (u|v<<16, t|m<<5)
      int u = pl.x & 0xffff, v = pl.x >> 16;
      int tix = pl.y & 31; unsigned m = pl.y >> 5;
      uint4 kup = ((const uint4*)(P + (size_t)u * F_TOT + 512))[l];
      float4 tvv = ((const float4*)TV4)[(size_t)v * 32 + tix];  // broadcast 16B
      float tv = (g & 2) ? ((g & 1) ? tvv.w : tvv.z) : ((g & 1) ? tvv.y : tvv.x);
      float k[8];
      unpk8(kup, k);
      float dq = 0.f;
#pragma unroll
      for (int j = 0; j < 8; j++) dq += qv[j] * k[j];
      float qk = hsum8(dq);
      if (valid && (l & 7) == 0){ qkb[(size_t)4 * m + g] = qk; tvb[(size_t)4 * m + g] = tv; }
      float w = qk * tv;
      float s = (w + __shfl_xor(w, 8, 64)) * (1.0f / 64.0f);
      if (valid && (l & 15) == 0) s3[2 * m + hg] = s;
      float ex = valid ? __expf(s) : 0.f;
      float et = ex * tv;
#pragma unroll
      for (int j = 0; j < 8; j++) acc[j] += et * k[j];
      zz += ex;
    }
#pragma unroll
    for (int j = 0; j < 8; j++) acc[j] += __shfl_xor(acc[j], 32, 64);
    zz += __shfl_xor(zz, 32, 64);
    float rz = (zz > 0.f) ? 1.0f / zz : 0.f;
    float coef = (-0.5f / 64.0f) * rz;
    if (z < 32){
      nt_store4((uint4*)(dP + (size_t)n * F_TOT + 256) + l,
                packbf(coef * acc[0], coef * acc[1]),
                packbf(coef * acc[2], coef * acc[3]),
                packbf(coef * acc[4], coef * acc[5]),
                packbf(coef * acc[6], coef * acc[7]));
      if ((l & 15) == 0) rz3[n * 2 + hg] = rz;
    }
    float eterm = (zz > 0.f) ? -0.5f * __logf(zz) : 0.f;   // lam3 = 0.5
    float eo = __shfl(eterm, 16, 64);
    if (z == 0) e_mot[n] = eterm + eo;
  } else {
    unsigned short us = ((const unsigned short*)(P + (size_t)n * F_TOT + 768))[z];
    float s = __uint_as_float((unsigned)us << 16);
    float mx = hmax32(s);
    float ex = __expf(s - mx);
    float se = hsum32(ex);
    float p = ex / se;
    bf16 pb = __float2bfloat16(p);
    ((unsigned short*)(dP + (size_t)n * F_TOT + 768))[z] = *(unsigned short*)&pb;
    float eterm = -(mx + __logf(se));
    float eo = __shfl(eterm, z ^ 32, 64);
    if (z == 0) e_mem[n] = eterm + eo;   // lamm=1, bm=1
  }
}

// ================ PHASE E: node_energy (128) | fused_uv (wide) ================
__global__ __launch_bounds__(256) void k_phaseE(const bf16* P, const uint2* leu,
                    const uint2* lmu, const uint2* lmv, const bf16* Ttb,
                    const float* s2, const float* rz2, const float* s3, const float* rz3,
                    const float* qkb, const float* tvb,
                    const int* off_eu, const int* off_mu, const int* off_mv, bf16* dP,
                    const float* e_node, const float* e_pair, const float* e_mot,
                    const float* e_mem, const int* batch, float* Eg){
  __shared__ float eg[NG_G];
  int b = blockIdx.x;
  if (b < 128){
    int t = threadIdx.x;
    if (t < NG_G) eg[t] = 0.f;
    __syncthreads();
    int n = b * 256 + t;
    float e = e_node[n] + e_pair[n] + e_mot[n] + e_mem[n];
    atomicAdd(&eg[batch[n]], e);
    __syncthreads();
    if (t < NG_G) atomicAdd(&Eg[t], eg[t]);
    return;
  }
  int b2 = b - 128;
  int type = b2 & 1, grp = b2 >> 1;
  int wave = threadIdx.x >> 6, z = threadIdx.x & 63;
  int n = grp * 4 + wave;
  int pn = pidx(n);

  if (type == 0){
    // dK2[u]: 8 edges per wave-iter, 8 lanes x 32B per edge
    int e8 = z >> 3, l8 = z & 7;
    int beg = off_eu[pn], end = off_eu[pn + 1];
    float acc[16];
#pragma unroll
    for (int j = 0; j < 16; j++) acc[j] = 0.f;
    int iters = (end - beg + 7) >> 3;
    for (int it = 0; it < iters; it++){
      int idx = beg + 8 * it + e8;
      bool valid = idx < end;
      int idc = valid ? idx : end - 1;
      uint2 pl = leu[idc];               // (c, eid)
      const uint4* qrow = (const uint4*)(P + (size_t)pl.x * F_TOT);
      uint4 qp0 = qrow[l8];
      uint4 qp1 = qrow[l8 + 8];
      float2 sv = *(const float2*)(s2 + 2 * (size_t)pl.y);
      float2 rv = *(const float2*)(rz2 + 2 * (size_t)pl.x);
      float qv0[8], qv1[8];
      unpk8(qp0, qv0); unpk8(qp1, qv1);
      float p0 = valid ? __expf(sv.x) * rv.x : 0.f;
      float p1 = valid ? __expf(sv.y) * rv.y : 0.f;
#pragma unroll
      for (int j = 0; j < 8; j++){
        acc[j]     += p0 * qv0[j];
        acc[8 + j] += p1 * qv1[j];
      }
    }
#pragma unroll
    for (int j = 0; j < 16; j++){
      acc[j] += __shfl_xor(acc[j], 8, 64);
      acc[j] += __shfl_xor(acc[j], 16, 64);
      acc[j] += __shfl_xor(acc[j], 32, 64);
    }
    if (z < 8){
      uint4* dst = (uint4*)(dP + (size_t)n * F_TOT + 128);
      nt_store4(dst + z,
                packbf(-0.125f * acc[0], -0.125f * acc[1]),
                packbf(-0.125f * acc[2], -0.125f * acc[3]),
                packbf(-0.125f * acc[4], -0.125f * acc[5]),
                packbf(-0.125f * acc[6], -0.125f * acc[7]));
      nt_store4(dst + z + 8,
                packbf(-0.125f * acc[8], -0.125f * acc[9]),
                packbf(-0.125f * acc[10], -0.125f * acc[11]),
                packbf(-0.125f * acc[12], -0.125f * acc[13]),
                packbf(-0.125f * acc[14], -0.125f * acc[15]));
    }
  } else {
    // dK3[n]: 4 motifs per wave-iter, 16 lanes x 32B per motif
    int m4 = z >> 4, l16 = z & 15;
    int g0 = l16 >> 3;                  // 0 or 1 (r index within head)
    float acc[16];
#pragma unroll
    for (int j = 0; j < 16; j++) acc[j] = 0.f;
    {
      int beg = off_mu[pn], end = off_mu[pn + 1];
      int iters = (end - beg + 3) >> 2;
      for (int it = 0; it < iters; it++){
        int idx = beg + 4 * it + m4;
        bool valid = idx < end;
        int idc = valid ? idx : end - 1;
        uint2 pl = lmu[idc];             // (c, m)
        const uint4* qrow = (const uint4*)(P + (size_t)pl.x * F_TOT + 256);
        uint4 qp0 = qrow[l16];
        uint4 qp1 = qrow[l16 + 16];
        float2 sv = *(const float2*)(s3 + 2 * (size_t)pl.y);
        float2 rv = *(const float2*)(rz3 + 2 * (size_t)pl.x);
        float4 tq = *(const float4*)(tvb + 4 * (size_t)pl.y);
        float t0 = g0 ? tq.y : tq.x;
        float t1 = g0 ? tq.w : tq.z;
        float qv0[8], qv1[8];
        unpk8(qp0, qv0); unpk8(qp1, qv1);
        float w0 = valid ? __expf(sv.x) * rv.x * t0 : 0.f;
        float w1 = valid ? __expf(sv.y) * rv.y * t1 : 0.f;
#pragma unroll
        for (int j = 0; j < 8; j++){
          acc[j]     += w0 * qv0[j];
          acc[8 + j] += w1 * qv1[j];
        }
      }
    }
    {
      int beg = off_mv[pn], end = off_mv[pn + 1];
      int iters = (end - beg + 3) >> 2;
      for (int it = 0; it < iters; it++){
        int idx = beg + 4 * it + m4;
        bool valid = idx < end;
        int idc = valid ? idx : end - 1;
        uint2 pl = lmv[idc];             // (c|t<<16, m)
        unsigned c = pl.x & 0xffff, tix = pl.x >> 16;
        const uint4* trow = (const uint4*)(Ttb + (size_t)tix * 256);
        uint4 tp0 = trow[l16];
        uint4 tp1 = trow[l16 + 16];
        float2 sv = *(const float2*)(s3 + 2 * (size_t)pl.y);
        float2 rv = *(const float2*)(rz3 + 2 * (size_t)c);
        float4 qq = *(const float4*)(qkb + 4 * (size_t)pl.y);
        float q0 = g0 ? qq.y : qq.x;
        float q1 = g0 ? qq.w : qq.z;
        float pt0[8], pt1[8];
        unpk8(tp0, pt0); unpk8(tp1, pt1);
        float w0 = valid ? __expf(sv.x) * rv.x * q0 : 0.f;
        float w1 = valid ? __expf(sv.y) * rv.y * q1 : 0.f;
#pragma unroll
        for (int j = 0; j < 8; j++){
          acc[j]     += w0 * pt0[j];
          acc[8 + j] += w1 * pt1[j];
        }
      }
    }
#pragma unroll
    for (int j = 0; j < 16; j++){
      acc[j] += __shfl_xor(acc[j], 16, 64);
      acc[j] += __shfl_xor(acc[j], 32, 64);
    }
    const float cst = -0.5f / 64.0f;
    if (z < 16){
      uint4* dst = (uint4*)(dP + (size_t)n * F_TOT + 512);
      nt_store4(dst + l16,
                packbf(cst * acc[0], cst * acc[1]),
                packbf(cst * acc[2], cst * acc[3]),
                packbf(cst * acc[4], cst * acc[5]),
                packbf(cst * acc[6], cst * acc[7]));
      nt_store4(dst + l16 + 16,
                packbf(cst * acc[8], cst * acc[9]),
                packbf(cst * acc[10], cst * acc[11]),
                packbf(cst * acc[12], cst * acc[13]),
                packbf(cst * acc[14], cst * acc[15]));
    }
  }
}

// ================ PHASE F: bwd GEMM via MFMA (full 26 K-tiles) ================
__global__ __launch_bounds__(256) void k_bwd_mfma(const bf16* dP, const bf16* wfB, float* dG){
  int wave = threadIdx.x >> 6, lane = threadIdx.x & 63;
  int m0 = blockIdx.x * 64 + wave * 16;
  int rw = lane & 15, quad = lane >> 4;
  const bf16* aptr = dP + (size_t)(m0 + rw) * F_TOT + quad * 8;
  f32x4 acc[8];
#pragma unroll
  for (int i = 0; i < 8; i++) acc[i] = (f32x4){0.f, 0.f, 0.f, 0.f};
  for (int kt = 0; kt < 26; kt++){
    bf16x8 a = *(const bf16x8*)(aptr + kt * 32);
#pragma unroll
    for (int td = 0; td < 8; td++){
      bf16x8 b = *(const bf16x8*)(wfB + (((size_t)td * 26 + kt) * 64 + lane) * 8);
      acc[td] = __builtin_amdgcn_mfma_f32_16x16x32_bf16(a, b, acc[td], 0, 0, 0);
    }
  }
#pragma unroll
  for (int td = 0; td < 8; td++){
    int col = td * 16 + rw;
#pragma unroll
    for (int r = 0; r < 4; r++){
      int row = m0 + quad * 4 + r;
      dG[(size_t)row * 128 + col] = acc[td][r];
    }
  }
}

// ================ PHASE G: finalize (wave/node) + Eg write ================
__global__ __launch_bounds__(256) void k_finalize(const float* X, const float* dG, const float* gamma,
                    const float* mu, const float* rstd, const float* step_p,
                    const float* Eg, float* out){
  int wave = threadIdx.x >> 6, l = threadIdx.x & 63;
  int n = blockIdx.x * 4 + wave;
  float2 x2 = ((const float2*)(X + (size_t)n * 128))[l];
  float2 dg2 = ((const float2*)(dG + (size_t)n * 128))[l];
  float2 gg = ((const float2*)gamma)[l];
  float rs = rstd[n], m = mu[n];
  float xh0 = (x2.x - m) * rs, xh1 = (x2.y - m) * rs;
  float dxh0 = dg2.x * gg.x, dxh1 = dg2.y * gg.y;
  float s1 = wsum64(dxh0 + dxh1);
  float s2v = wsum64(dxh0 * xh0 + dxh1 * xh1);
  float g0 = x2.x + rs * (dxh0 - s1 * (1.0f / 128) - xh0 * (s2v * (1.0f / 128)));
  float g1 = x2.y + rs * (dxh1 - s1 * (1.0f / 128) - xh1 * (s2v * (1.0f / 128)));
  float gn = sqrtf(wsum64(g0 * g0 + g1 * g1));
  float gc = 1.0f / fmaxf(gn, 1.0f);
  g0 *= gc; g1 *= gc;
  float step = step_p[0];
  float xn0 = x2.x - step * g0, xn1 = x2.y - step * g1;
  float sn = sqrtf(wsum64(xn0 * xn0 + xn1 * xn1));
  float sc = 10.0f / fmaxf(sn, 10.0f);
  ((float2*)(out + (size_t)n * 128))[l] = make_float2(xn0 * sc, xn1 * sc);
  if (blockIdx.x == 0 && threadIdx.x < NG_G)
    out[(size_t)N_NODES * 128 + threadIdx.x] = Eg[threadIdx.x];
}

extern "C" void kernel_launch(void* const* d_in, const int* in_sizes, int n_in,
                              void* d_out, int out_size, void* d_ws, size_t ws_size,
                              hipStream_t stream) {
  const float* X     = (const float*)d_in[0];
  const int*  c_2    = (const int*) d_in[1];
  const int*  u_2    = (const int*) d_in[2];
  const int*  c_3    = (const int*) d_in[3];
  const int*  u_3    = (const int*) d_in[4];
  const int*  v_3    = (const int*) d_in[5];
  const int*  t_tau  = (const int*) d_in[6];
  const int*  batch  = (const int*) d_in[7];
  const float* a_2   = (const float*)d_in[8];
  const float* step_s= (const float*)d_in[9];
  const float* ln_g  = (const float*)d_in[10];
  const float* ln_b  = (const float*)d_in[11];
  const float* W_Q2  = (const float*)d_in[12];
  const float* W_K2  = (const float*)d_in[13];
  const float* W_Q3  = (const float*)d_in[14];
  const float* W_K3  = (const float*)d_in[15];
  const float* T_tau = (const float*)d_in[16];
  const float* W_Qm  = (const float*)d_in[17];
  const float* W_Km  = (const float*)d_in[18];
  const float* B_mem = (const float*)d_in[19];
  float* out = (float*)d_out;

  char* wb = (char*)d_ws;
  float* Wcat   = (float*)wb; wb += 768 * D_DIM * 4;
  float* Mprod  = (float*)wb; wb += 8192 * 4;
  float* mu     = (float*)wb; wb += N_NODES * 4;
  float* rstd   = (float*)wb; wb += N_NODES * 4;
  float* s2     = (float*)wb; wb += (size_t)E_EDG * 2 * 4;
  float* rz2    = (float*)wb; wb += N_NODES * 2 * 4;
  float* s3     = (float*)wb; wb += (size_t)M_MOT * 2 * 4;
  float* qkb    = (float*)wb; wb += (size_t)M_MOT * 4 * 4;
  float* tvb    = (float*)wb; wb += (size_t)M_MOT * 4 * 4;
  float* rz3    = (float*)wb; wb += N_NODES * 2 * 4;
  float* e_node = (float*)wb; wb += N_NODES * 4;
  float* e_pair = (float*)wb; wb += N_NODES * 4;
  float* e_mot  = (float*)wb; wb += N_NODES * 4;
  float* e_mem  = (float*)wb; wb += N_NODES * 4;
  float* Eg     = (float*)wb; wb += NG_G * 4;
  float* dG     = (float*)wb; wb += (size_t)N_NODES * D_DIM * 4;
  float* TV4    = (float*)wb; wb += (size_t)N_NODES * 32 * 4 * 4;  // 16.8MB
  bf16* Gb      = (bf16*)wb;  wb += (size_t)N_NODES * D_DIM * 2;
  bf16* P       = (bf16*)wb;  wb += (size_t)N_NODES * F_TOT * 2;
  bf16* dP      = (bf16*)wb;  wb += (size_t)N_NODES * F_TOT * 2;
  bf16* wfF     = (bf16*)wb;  wb += 106496 * 2;
  bf16* wfB     = (bf16*)wb;  wb += 106496 * 2;
  bf16* Ttb     = (bf16*)wb;  wb += 8192 * 2;
  int* cntcur   = (int*)wb;   wb += 8 * 5 * N_NODES * 4;   // 8 per-XCD copies
  int* off      = (int*)wb;   wb += 5 * (N_NODES + 1) * 4;
  wb = (char*)(((size_t)wb + 15) & ~(size_t)15);
  uint2* lec    = (uint2*)wb; wb += (size_t)E_EDG * 8;
  uint2* leu    = (uint2*)wb; wb += (size_t)E_EDG * 8;
  uint2* lmc    = (uint2*)wb; wb += (size_t)M_MOT * 8;
  uint2* lmu    = (uint2*)wb; wb += (size_t)M_MOT * 8;
  uint2* lmv    = (uint2*)wb; wb += (size_t)M_MOT * 8;

  const int* off_ec = off;
  const int* off_eu = off + (N_NODES + 1);
  const int* off_mc = off + 2 * (N_NODES + 1);
  const int* off_mu = off + 3 * (N_NODES + 1);
  const int* off_mv = off + 4 * (N_NODES + 1);

  hipMemsetAsync(cntcur, 0, (size_t)8 * 5 * N_NODES * sizeof(int), stream);
  hipMemsetAsync(Eg, 0, NG_G * sizeof(float), stream);
  hipLaunchKernelGGL(k_phaseA, dim3(1504), dim3(256), 0, stream,
                     c_2, u_2, c_3, u_3, v_3, W_Q2, W_K2, W_Q3, W_K3,
                     W_Qm, W_Km, B_mem, T_tau, cntcur, Wcat, Ttb, Mprod);
  hipLaunchKernelGGL(k_reduce8, dim3(160), dim3(256), 0, stream, cntcur);
  hipLaunchKernelGGL(k_phaseB, dim3(2157), dim3(1024), 0, stream,
                     cntcur, off, X, ln_g, ln_b, Gb, mu, rstd, e_node,
                     Wcat, Mprod, wfF, wfB);
  hipLaunchKernelGGL(k_phaseC, dim3(512 * 29), dim3(256), 0, stream,
                     Gb, wfF, P, c_2, u_2, c_3, u_3, v_3, t_tau, cntcur,
                     lec, leu, lmc, lmu, lmv);
  hipLaunchKernelGGL(k_tv, dim3(512), dim3(256), 0, stream, P, Ttb, TV4);
  hipLaunchKernelGGL(k_fused_c, dim3(3 * (N_NODES / 4)), dim3(256), 0, stream,
                     P, lec, lmc, Ttb, TV4, a_2, off_ec, off_mc,
                     s2, rz2, s3, qkb, tvb, rz3, dP, e_pair, e_mot, e_mem);
  hipLaunchKernelGGL(k_phaseE, dim3(128 + 2 * (N_NODES / 4)), dim3(256), 0, stream,
                     P, leu, lmu, lmv, Ttb, s2, rz2, s3, rz3, qkb, tvb,
                     off_eu, off_mu, off_mv, dP,
                     e_node, e_pair, e_mot, e_mem, batch, Eg);
  hipLaunchKernelGGL(k_bwd_mfma, dim3(N_NODES / 64), dim3(256), 0, stream, dP, wfB, dG);
  hipLaunchKernelGGL(k_finalize, dim3(N_NODES / 4), dim3(256), 0, stream,
                     X, dG, ln_g, mu, rstd, step_s, Eg, out);
}

// Round 9
// 391.123 us; speedup vs baseline: 1.0958x; 1.0958x over previous
//
#include <hip/hip_runtime.h>
#include <hip/hip_bf16.h>
#include <math.h>

typedef __hip_bfloat16 bf16;
typedef short bf16x8 __attribute__((ext_vector_type(8)));
typedef float f32x4 __attribute__((ext_vector_type(4)));

#define N_NODES 32768
#define D_DIM 128
#define E_EDG 262144
#define M_MOT 131072
#define NG_G 32
#define F_TOT 832
// P: Q2[0,128) K2[128,256) Q3[256,512) K3[512,768) S_mem[768,832)
// dP: dQ2 dK2 dQ3 dK3 Pm ; -0.125*Km@W_Qm folded into bwd B-frags
// lam2=1 lam3=0.5 lamm=1 b2=b3=bm=1 ; no-max softmax, z as reciprocal
// R14: phaseC P-store via LDS tile. R15: XCD-local fill scatter.
// R16: wide phaseE. R17: k_reduce8 + int4 scan. R18: narrow fused_c.
// R19: __expf/__logf. R20: TV precompute (fused_c 57->53, FETCH 124->102MB).
// R21: REVERTED. NT stores/loads regressed phaseC 55.6->85.5us (gfx950 NT
//      appears to force write-through; WRITE rose to 119MB).
// R22: stream separation instead. phaseC's +51MB write amplification =
//      P-store stream cycling L2 and evicting partially-filled 8B list
//      lines between their ~8 writes. Split: k_fill (scatter only, lists
//      stay hot in L2) + k_phaseC_gemm (streaming only) + k_tv.

__device__ __forceinline__ int pidx(int n){ return ((n & 7) << 12) | (n >> 3); }

__device__ __forceinline__ float wsum64(float v){
#pragma unroll
  for (int o = 32; o > 0; o >>= 1) v += __shfl_xor(v, o, 64);
  return v;
}
__device__ __forceinline__ float hsum32(float v){
#pragma unroll
  for (int o = 16; o > 0; o >>= 1) v += __shfl_xor(v, o, 64);
  return v;
}
__device__ __forceinline__ float hmax32(float v){
#pragma unroll
  for (int o = 16; o > 0; o >>= 1) v = fmaxf(v, __shfl_xor(v, o, 64));
  return v;
}
__device__ __forceinline__ float hsum8(float v){
#pragma unroll
  for (int o = 4; o > 0; o >>= 1) v += __shfl_xor(v, o, 64);
  return v;
}
__device__ __forceinline__ float bflo(unsigned u){ return __uint_as_float(u << 16); }
__device__ __forceinline__ float bfhi(unsigned u){ return __uint_as_float(u & 0xffff0000u); }
__device__ __forceinline__ unsigned packbf(float x, float y){
  bf16 a = __float2bfloat16(x), b = __float2bfloat16(y);
  unsigned short ua = *(unsigned short*)&a, ub = *(unsigned short*)&b;
  return (unsigned)ua | ((unsigned)ub << 16);
}
__device__ __forceinline__ void unpk8(uint4 p, float* f){
  f[0] = bflo(p.x); f[1] = bfhi(p.x); f[2] = bflo(p.y); f[3] = bfhi(p.y);
  f[4] = bflo(p.z); f[5] = bfhi(p.z); f[6] = bflo(p.w); f[7] = bfhi(p.w);
}

// ================ PHASE A: hist (per-XCD copies) | Wcat/Ttb prep | Mprod ================
__global__ __launch_bounds__(256) void k_phaseA(
    const int* c2, const int* u2, const int* c3, const int* u3, const int* v3,
    const float* wq2, const float* wk2, const float* wq3, const float* wk3,
    const float* wqm, const float* wkm, const float* bmem, const float* Ttau,
    int* cnt, float* Wcat, bf16* Ttb, float* Mprod){
  __shared__ float KmL[64];
  int b = blockIdx.x, t = threadIdx.x;
  if (b < 1024){
    int* base = cnt + (size_t)(b & 7) * 5 * N_NODES;   // per-XCD private copy
    int i = b * 256 + t;
    atomicAdd(&base[pidx(c2[i])], 1);
    atomicAdd(&base[N_NODES + pidx(u2[i])], 1);
    if (i < M_MOT){
      atomicAdd(&base[2 * N_NODES + pidx(c3[i])], 1);
      atomicAdd(&base[3 * N_NODES + pidx(u3[i])], 1);
      atomicAdd(&base[4 * N_NODES + pidx(v3[i])], 1);
    }
  } else if (b < 1440){
    int idx = (b - 1024) * 256 + t;
    if (idx < 768 * D_DIM){
      int f = idx / D_DIM, d = idx - f * D_DIM;
      const float* src; int fr;
      if      (f < 128){ src = wq2; fr = f; }
      else if (f < 256){ src = wk2; fr = f - 128; }
      else if (f < 512){ src = wq3; fr = f - 256; }
      else             { src = wk3; fr = f - 512; }
      Wcat[f * D_DIM + d] = src[fr * D_DIM + d];
    } else {
      int j = idx - 768 * D_DIM; // < 8192
      Ttb[j] = __float2bfloat16(Ttau[j]);
    }
  } else {
    int hk = b - 1440;            // 0..63
    int h = hk >> 5, k = hk & 31;
    if (t < 64){
      const float* wrow = wkm + (size_t)(h * 64 + t) * D_DIM;
      const float* brow = bmem + k * D_DIM;
      float acc = 0.f;
      for (int d = 0; d < D_DIM; d++) acc += wrow[d] * brow[d];
      KmL[t] = acc;
    }
    __syncthreads();
    if (t < 128){
      const float* w = wqm + (size_t)(h * 64) * 128 + t;
      float acc = 0.f;
      for (int z = 0; z < 64; z++) acc += w[z * 128] * KmL[z];
      Mprod[t * 64 + hk] = acc;
    }
  }
}

// ================ REDUCE8: sum 8 hist copies into copy 0 (int4, 160 blocks) ================
__global__ __launch_bounds__(256) void k_reduce8(int* cnt){
  int idx = blockIdx.x * 256 + threadIdx.x;     // over 5*N/4 = 40960 int4s
  int4* base = (int4*)cnt;
  int4 s = base[idx];
#pragma unroll
  for (int rr = 1; rr < 8; rr++){
    int4 v = *(const int4*)(cnt + (size_t)rr * 5 * N_NODES + 4 * (size_t)idx);
    s.x += v.x; s.y += v.y; s.z += v.z; s.w += v.w;
  }
  base[idx] = s;
}

// ================ PHASE B: scan (copy 0, int4) | layernorm | pack_frags ================
__global__ __launch_bounds__(1024) void k_phaseB(
    int* cntcur, int* off,
    const float* X, const float* gamma, const float* beta,
    bf16* Gb, float* mu, float* rstd, float* e_node,
    const float* Wcat, const float* Mprod, bf16* wfF, bf16* wfB){
  __shared__ int sd[1024];
  int b = blockIdx.x, t = threadIdx.x;
  if (b < 5){
    int* c = cntcur + b * N_NODES;
    int* o = off + b * (N_NODES + 1);
    int4 lv[8];
    const int4* c4 = (const int4*)c;
#pragma unroll
    for (int j4 = 0; j4 < 8; j4++) lv[j4] = c4[t * 8 + j4];
    int* lvp = (int*)lv;
    int loc[32];
    int sum = 0;
#pragma unroll
    for (int j = 0; j < 32; j++){ loc[j] = sum; sum += lvp[j]; }
    sd[t] = sum;
    __syncthreads();
    for (int s = 1; s < 1024; s <<= 1){
      int v = (t >= s) ? sd[t - s] : 0;
      __syncthreads();
      sd[t] += v;
      __syncthreads();
    }
    int excl = sd[t] - sum;
#pragma unroll
    for (int j = 0; j < 32; j++){
      int val = excl + loc[j];
      o[t * 32 + j] = val;
      c[t * 32 + j] = val;         // copy 0 becomes "cur" for the fill
    }
    if (t == 1023) o[N_NODES] = sd[1023];
  } else if (b < 2053){
    int wv = t >> 6, l = t & 63;
    int n = (b - 5) * 16 + wv;
    float2 x2 = ((const float2*)(X + (size_t)n * 128))[l];
    float sumx = wsum64(x2.x + x2.y);
    float sumxx = wsum64(x2.x * x2.x + x2.y * x2.y);
    float m = sumx * (1.0f / 128.0f);
    float var = sumxx * (1.0f / 128.0f) - m * m;
    float rs = rsqrtf(var + 1e-5f);
    float2 gg = ((const float2*)gamma)[l];
    float2 bb = ((const float2*)beta)[l];
    ((unsigned*)(Gb + (size_t)n * 128))[l] =
        packbf(gg.x * (x2.x - m) * rs + bb.x, gg.y * (x2.y - m) * rs + bb.y);
    if (l == 0){ mu[n] = m; rstd[n] = rs; e_node[n] = 0.5f * sumxx; }
  } else {
    int idx = (b - 2053) * 1024 + t;   // < 106496
    int j = idx & 7, lane = (idx >> 3) & 63, tt = idx >> 9;
    {
      int tn = tt >> 2, kt = tt & 3;
      int f = tn * 16 + (lane & 15), d = kt * 32 + (lane >> 4) * 8 + j;
      float v = (f < 768) ? Wcat[f * 128 + d] : 0.125f * Mprod[d * 64 + (f - 768)];
      wfF[idx] = __float2bfloat16(v);
    }
    {
      int td = tt / 26, tf = tt - td * 26;
      int f = tf * 32 + (lane >> 4) * 8 + j, d = td * 16 + (lane & 15);
      float v = (f < 768) ? Wcat[f * 128 + d] : -0.125f * Mprod[d * 64 + (f - 768)];
      wfB[idx] = __float2bfloat16(v);
    }
  }
}

// ================ FILL: residue-owned list build (scatter only, 8192 blocks) ================
__global__ __launch_bounds__(256) void k_fill(
    const int* c2, const int* u2, const int* c3, const int* u3, const int* v3,
    const int* t3, int* cur,
    uint2* lec, uint2* leu, uint2* lmc, uint2* lmu, uint2* lmv){
  int b = blockIdx.x;            // 8 consecutive blocks per range
  int range = b >> 3;
  int res = b & 7;               // residue ownership == XCD under round-robin
  int i = range * 256 + threadIdx.x;
  {
    int c = c2[i], u = u2[i];
    if ((c & 7) == res){
      int pos = atomicAdd(&cur[pidx(c)], 1);
      lec[pos] = make_uint2((unsigned)u, (unsigned)i);
    }
    if ((u & 7) == res){
      int pos = atomicAdd(&cur[N_NODES + pidx(u)], 1);
      leu[pos] = make_uint2((unsigned)c, (unsigned)i);
    }
  }
  if (i < M_MOT){
    int c = c3[i], u = u3[i], v = v3[i], mt = t3[i];
    if ((c & 7) == res){
      int pos = atomicAdd(&cur[2 * N_NODES + pidx(c)], 1);
      lmc[pos] = make_uint2((unsigned)(u | (v << 16)), (unsigned)(mt | (i << 5)));
    }
    if ((u & 7) == res){
      int pos = atomicAdd(&cur[3 * N_NODES + pidx(u)], 1);
      lmu[pos] = make_uint2((unsigned)c, (unsigned)i);
    }
    if ((v & 7) == res){
      int pos = atomicAdd(&cur[4 * N_NODES + pidx(v)], 1);
      lmv[pos] = make_uint2((unsigned)(c | (mt << 16)), (unsigned)i);
    }
  }
}

// ================ PHASE C: fwd GEMM only (6656 blocks, streaming) ================
__global__ __launch_bounds__(256) void k_phaseC_gemm(
    const bf16* Gb, const bf16* wfF, bf16* P){
  // 64x64 output tile, LDS-staged for sector-aligned coalesced stores.
  __shared__ unsigned shP[64 * 36];
  int f = blockIdx.x;
  int bx = f & 511, by = f >> 9;
  int wave = threadIdx.x >> 6, lane = threadIdx.x & 63;
  int m0 = bx * 64 + wave * 16;
  int tn0 = by * 4;
  int rw = lane & 15, quad = lane >> 4;
  const bf16* aptr = Gb + (size_t)(m0 + rw) * 128 + quad * 8;
  bf16x8 a[4];
#pragma unroll
  for (int kt = 0; kt < 4; kt++) a[kt] = *(const bf16x8*)(aptr + kt * 32);
  f32x4 acc[4];
#pragma unroll
  for (int i = 0; i < 4; i++) acc[i] = (f32x4){0.f, 0.f, 0.f, 0.f};
#pragma unroll
  for (int nf = 0; nf < 4; nf++){
    int tn = tn0 + nf;
#pragma unroll
    for (int kt = 0; kt < 4; kt++){
      bf16x8 bb = *(const bf16x8*)(wfF + (((size_t)tn * 4 + kt) * 64 + lane) * 8);
      acc[nf] = __builtin_amdgcn_mfma_f32_16x16x32_bf16(bb, a[kt], acc[nf], 0, 0, 0);
    }
  }
  int lrow = wave * 16 + rw;
#pragma unroll
  for (int nf = 0; nf < 4; nf++){
    unsigned lo = packbf(acc[nf][0], acc[nf][1]);
    unsigned hi = packbf(acc[nf][2], acc[nf][3]);
    *(uint2*)&shP[lrow * 36 + nf * 8 + quad * 2] = make_uint2(lo, hi);
  }
  __syncthreads();
  int t = threadIdx.x;
  int orow = t >> 2, s = t & 3;
  uint4 v0 = *(const uint4*)&shP[orow * 36 + s * 4];
  uint4 v1 = *(const uint4*)&shP[orow * 36 + 16 + s * 4];
  uint4* prow = (uint4*)(P + (size_t)(bx * 64 + orow) * F_TOT) + tn0 * 2 + s;
  prow[0] = v0;
  prow[4] = v1;
}

// ================ TV precompute: TV4[node][t] = {<T[t,hr,:],K3[node,hr,:]>}_hr0..3 ================
__global__ __launch_bounds__(256) void k_tv(const bf16* P, const bf16* Ttb, float* TV4){
  __shared__ float sh[64 * 132];   // node-major, stride 132 dwords (pad vs 128)
  int blk = blockIdx.x;            // 512 blocks x 64 nodes
  int wave = threadIdx.x >> 6, lane = threadIdx.x & 63;
  int rw = lane & 15, quad = lane >> 4;
  int m0 = blk * 64 + wave * 16;
  const bf16* kbase = P + (size_t)(m0 + rw) * F_TOT + 512 + quad * 8;
#pragma unroll
  for (int hr = 0; hr < 4; hr++){
    bf16x8 a0 = *(const bf16x8*)(kbase + hr * 64);
    bf16x8 a1 = *(const bf16x8*)(kbase + hr * 64 + 32);
    f32x4 acc0 = (f32x4){0.f,0.f,0.f,0.f};
    f32x4 acc1 = (f32x4){0.f,0.f,0.f,0.f};
    {
      const bf16* tb = Ttb + (size_t)rw * 256 + hr * 64 + quad * 8;
      bf16x8 t0 = *(const bf16x8*)(tb);
      bf16x8 t1 = *(const bf16x8*)(tb + 32);
      acc0 = __builtin_amdgcn_mfma_f32_16x16x32_bf16(t0, a0, acc0, 0, 0, 0);
      acc0 = __builtin_amdgcn_mfma_f32_16x16x32_bf16(t1, a1, acc0, 0, 0, 0);
    }
    {
      const bf16* tb = Ttb + (size_t)(16 + rw) * 256 + hr * 64 + quad * 8;
      bf16x8 t0 = *(const bf16x8*)(tb);
      bf16x8 t1 = *(const bf16x8*)(tb + 32);
      acc1 = __builtin_amdgcn_mfma_f32_16x16x32_bf16(t0, a0, acc1, 0, 0, 0);
      acc1 = __builtin_amdgcn_mfma_f32_16x16x32_bf16(t1, a1, acc1, 0, 0, 0);
    }
    int lrow = wave * 16 + rw;
#pragma unroll
    for (int r_ = 0; r_ < 4; r_++){
      sh[lrow * 132 + (quad * 4 + r_) * 4 + hr] = acc0[r_];
      sh[lrow * 132 + (16 + quad * 4 + r_) * 4 + hr] = acc1[r_];
    }
  }
  __syncthreads();
  int t = threadIdx.x;
#pragma unroll
  for (int it = 0; it < 8; it++){
    int idx4 = it * 256 + t;             // [0, 2048): node*32 + t
    int node = idx4 >> 5, toff = (idx4 & 31) * 4;
    float4 v = *(const float4*)&sh[node * 132 + toff];
    ((float4*)TV4)[(size_t)blk * 2048 + idx4] = v;
  }
}

// ================ PHASE D: fused forward gathers (narrow; TV table for tv) ================
__global__ __launch_bounds__(256) void k_fused_c(const bf16* P, const uint2* lec, const uint2* lmc,
                   const bf16* Ttb, const float* TV4, const float* a2,
                   const int* off_ec, const int* off_mc,
                   float* s2, float* rz2, float* s3, float* qkb, float* tvb, float* rz3,
                   bf16* dP, float* e_pair, float* e_mot, float* e_mem){
  int b = blockIdx.x;
  int type = b % 3, grp = b / 3;
  int wave = threadIdx.x >> 6, z = threadIdx.x & 63;
  int n = grp * 4 + wave;
  int l = z & 31, lh = z >> 5;
  int pn = pidx(n);

  if (type == 0){
    // ---- edges: 4 per wave (16-lane groups), 8-lane head sub-groups ----
    int q = z >> 4, l16 = z & 15, hg = l16 >> 3;
    int beg = off_ec[pn], end = off_ec[pn + 1];
    uint4 qp = ((const uint4*)(P + (size_t)n * F_TOT))[l16];
    float qv[8]; unpk8(qp, qv);
    float acc[8] = {0,0,0,0,0,0,0,0};
    float zz = 0.f;
    int iters = (end - beg + 3) >> 2;
    for (int it = 0; it < iters; it++){
      int idx = beg + 4 * it + q;
      bool valid = idx < end;
      int idc = valid ? idx : end - 1;
      uint2 pl = lec[idc];               // (u, eid)
      float2 av = *(const float2*)(a2 + (size_t)pl.y * 2);
      uint4 kp = ((const uint4*)(P + (size_t)pl.x * F_TOT + 128))[l16];
      float kv[8]; unpk8(kp, kv);
      float d = 0.f;
#pragma unroll
      for (int j = 0; j < 8; j++) d += qv[j] * kv[j];
      float s = hsum8(d) * 0.125f + (hg ? av.y : av.x);
      if (valid && (l16 & 7) == 0) s2[2 * pl.y + hg] = s;
      float ex = valid ? __expf(s) : 0.f;
#pragma unroll
      for (int j = 0; j < 8; j++) acc[j] += ex * kv[j];
      zz += ex;
    }
#pragma unroll
    for (int j = 0; j < 8; j++){
      acc[j] += __shfl_xor(acc[j], 16, 64);
      acc[j] += __shfl_xor(acc[j], 32, 64);
    }
    zz += __shfl_xor(zz, 16, 64);
    zz += __shfl_xor(zz, 32, 64);
    float rz = (zz > 0.f) ? 1.0f / zz : 0.f;
    float coef = -0.125f * rz;
    if (z < 16){
      uint4 o;
      o.x = packbf(coef * acc[0], coef * acc[1]);
      o.y = packbf(coef * acc[2], coef * acc[3]);
      o.z = packbf(coef * acc[4], coef * acc[5]);
      o.w = packbf(coef * acc[6], coef * acc[7]);
      ((uint4*)(dP + (size_t)n * F_TOT))[l16] = o;
      if ((l16 & 7) == 0) rz2[n * 2 + hg] = rz;
    }
    float eterm = (zz > 0.f) ? -__logf(zz) : 0.f;   // lam2 = 1
    float eo = __shfl(eterm, 8, 64);
    if (z == 0) e_pair[n] = eterm + eo;
  } else if (type == 1){
    // ---- motifs: 2 per wave (32-lane halves), 8-lane hr groups; tv from TV4 ----
    int g = l >> 3, hg = g >> 1;
    int beg = off_mc[pn], end = off_mc[pn + 1];
    uint4 qp = ((const uint4*)(P + (size_t)n * F_TOT + 256))[l];
    float qv[8]; unpk8(qp, qv);
    float acc[8] = {0,0,0,0,0,0,0,0};
    float zz = 0.f;
    int iters = (end - beg + 1) >> 1;
    for (int it = 0; it < iters; it++){
      int idx = beg + 2 * it + lh;
      bool valid = idx < end;
      int idc = valid ? idx : end - 1;
      uint2 pl = lmc[idc];               // (u|v<<16, t|m<<5)
      int u = pl.x & 0xffff, v = pl.x >> 16;
      int tix = pl.y & 31; unsigned m = pl.y >> 5;
      uint4 kup = ((const uint4*)(P + (size_t)u * F_TOT + 512))[l];
      float4 tvv = ((const float4*)TV4)[(size_t)v * 32 + tix];  // broadcast 16B
      float tv = (g & 2) ? ((g & 1) ? tvv.w : tvv.z) : ((g & 1) ? tvv.y : tvv.x);
      float k[8];
      unpk8(kup, k);
      float dq = 0.f;
#pragma unroll
      for (int j = 0; j < 8; j++) dq += qv[j] * k[j];
      float qk = hsum8(dq);
      if (valid && (l & 7) == 0){ qkb[(size_t)4 * m + g] = qk; tvb[(size_t)4 * m + g] = tv; }
      float w = qk * tv;
      float s = (w + __shfl_xor(w, 8, 64)) * (1.0f / 64.0f);
      if (valid && (l & 15) == 0) s3[2 * m + hg] = s;
      float ex = valid ? __expf(s) : 0.f;
      float et = ex * tv;
#pragma unroll
      for (int j = 0; j < 8; j++) acc[j] += et * k[j];
      zz += ex;
    }
#pragma unroll
    for (int j = 0; j < 8; j++) acc[j] += __shfl_xor(acc[j], 32, 64);
    zz += __shfl_xor(zz, 32, 64);
    float rz = (zz > 0.f) ? 1.0f / zz : 0.f;
    float coef = (-0.5f / 64.0f) * rz;
    if (z < 32){
      uint4 o;
      o.x = packbf(coef * acc[0], coef * acc[1]);
      o.y = packbf(coef * acc[2], coef * acc[3]);
      o.z = packbf(coef * acc[4], coef * acc[5]);
      o.w = packbf(coef * acc[6], coef * acc[7]);
      ((uint4*)(dP + (size_t)n * F_TOT + 256))[l] = o;
      if ((l & 15) == 0) rz3[n * 2 + hg] = rz;
    }
    float eterm = (zz > 0.f) ? -0.5f * __logf(zz) : 0.f;   // lam3 = 0.5
    float eo = __shfl(eterm, 16, 64);
    if (z == 0) e_mot[n] = eterm + eo;
  } else {
    unsigned short us = ((const unsigned short*)(P + (size_t)n * F_TOT + 768))[z];
    float s = __uint_as_float((unsigned)us << 16);
    float mx = hmax32(s);
    float ex = __expf(s - mx);
    float se = hsum32(ex);
    float p = ex / se;
    bf16 pb = __float2bfloat16(p);
    ((unsigned short*)(dP + (size_t)n * F_TOT + 768))[z] = *(unsigned short*)&pb;
    float eterm = -(mx + __logf(se));
    float eo = __shfl(eterm, z ^ 32, 64);
    if (z == 0) e_mem[n] = eterm + eo;   // lamm=1, bm=1
  }
}

// ================ PHASE E: node_energy (128) | fused_uv (wide) ================
__global__ __launch_bounds__(256) void k_phaseE(const bf16* P, const uint2* leu,
                    const uint2* lmu, const uint2* lmv, const bf16* Ttb,
                    const float* s2, const float* rz2, const float* s3, const float* rz3,
                    const float* qkb, const float* tvb,
                    const int* off_eu, const int* off_mu, const int* off_mv, bf16* dP,
                    const float* e_node, const float* e_pair, const float* e_mot,
                    const float* e_mem, const int* batch, float* Eg){
  __shared__ float eg[NG_G];
  int b = blockIdx.x;
  if (b < 128){
    int t = threadIdx.x;
    if (t < NG_G) eg[t] = 0.f;
    __syncthreads();
    int n = b * 256 + t;
    float e = e_node[n] + e_pair[n] + e_mot[n] + e_mem[n];
    atomicAdd(&eg[batch[n]], e);
    __syncthreads();
    if (t < NG_G) atomicAdd(&Eg[t], eg[t]);
    return;
  }
  int b2 = b - 128;
  int type = b2 & 1, grp = b2 >> 1;
  int wave = threadIdx.x >> 6, z = threadIdx.x & 63;
  int n = grp * 4 + wave;
  int pn = pidx(n);

  if (type == 0){
    // dK2[u]: 8 edges per wave-iter, 8 lanes x 32B per edge
    int e8 = z >> 3, l8 = z & 7;
    int beg = off_eu[pn], end = off_eu[pn + 1];
    float acc[16];
#pragma unroll
    for (int j = 0; j < 16; j++) acc[j] = 0.f;
    int iters = (end - beg + 7) >> 3;
    for (int it = 0; it < iters; it++){
      int idx = beg + 8 * it + e8;
      bool valid = idx < end;
      int idc = valid ? idx : end - 1;
      uint2 pl = leu[idc];               // (c, eid)
      const uint4* qrow = (const uint4*)(P + (size_t)pl.x * F_TOT);
      uint4 qp0 = qrow[l8];
      uint4 qp1 = qrow[l8 + 8];
      float2 sv = *(const float2*)(s2 + 2 * (size_t)pl.y);
      float2 rv = *(const float2*)(rz2 + 2 * (size_t)pl.x);
      float qv0[8], qv1[8];
      unpk8(qp0, qv0); unpk8(qp1, qv1);
      float p0 = valid ? __expf(sv.x) * rv.x : 0.f;
      float p1 = valid ? __expf(sv.y) * rv.y : 0.f;
#pragma unroll
      for (int j = 0; j < 8; j++){
        acc[j]     += p0 * qv0[j];
        acc[8 + j] += p1 * qv1[j];
      }
    }
#pragma unroll
    for (int j = 0; j < 16; j++){
      acc[j] += __shfl_xor(acc[j], 8, 64);
      acc[j] += __shfl_xor(acc[j], 16, 64);
      acc[j] += __shfl_xor(acc[j], 32, 64);
    }
    if (z < 8){
      uint4 o0, o1;
      o0.x = packbf(-0.125f * acc[0], -0.125f * acc[1]);
      o0.y = packbf(-0.125f * acc[2], -0.125f * acc[3]);
      o0.z = packbf(-0.125f * acc[4], -0.125f * acc[5]);
      o0.w = packbf(-0.125f * acc[6], -0.125f * acc[7]);
      o1.x = packbf(-0.125f * acc[8], -0.125f * acc[9]);
      o1.y = packbf(-0.125f * acc[10], -0.125f * acc[11]);
      o1.z = packbf(-0.125f * acc[12], -0.125f * acc[13]);
      o1.w = packbf(-0.125f * acc[14], -0.125f * acc[15]);
      uint4* dst = (uint4*)(dP + (size_t)n * F_TOT + 128);
      dst[z] = o0;
      dst[z + 8] = o1;
    }
  } else {
    // dK3[n]: 4 motifs per wave-iter, 16 lanes x 32B per motif
    int m4 = z >> 4, l16 = z & 15;
    int g0 = l16 >> 3;                  // 0 or 1 (r index within head)
    float acc[16];
#pragma unroll
    for (int j = 0; j < 16; j++) acc[j] = 0.f;
    {
      int beg = off_mu[pn], end = off_mu[pn + 1];
      int iters = (end - beg + 3) >> 2;
      for (int it = 0; it < iters; it++){
        int idx = beg + 4 * it + m4;
        bool valid = idx < end;
        int idc = valid ? idx : end - 1;
        uint2 pl = lmu[idc];             // (c, m)
        const uint4* qrow = (const uint4*)(P + (size_t)pl.x * F_TOT + 256);
        uint4 qp0 = qrow[l16];
        uint4 qp1 = qrow[l16 + 16];
        float2 sv = *(const float2*)(s3 + 2 * (size_t)pl.y);
        float2 rv = *(const float2*)(rz3 + 2 * (size_t)pl.x);
        float4 tq = *(const float4*)(tvb + 4 * (size_t)pl.y);
        float t0 = g0 ? tq.y : tq.x;
        float t1 = g0 ? tq.w : tq.z;
        float qv0[8], qv1[8];
        unpk8(qp0, qv0); unpk8(qp1, qv1);
        float w0 = valid ? __expf(sv.x) * rv.x * t0 : 0.f;
        float w1 = valid ? __expf(sv.y) * rv.y * t1 : 0.f;
#pragma unroll
        for (int j = 0; j < 8; j++){
          acc[j]     += w0 * qv0[j];
          acc[8 + j] += w1 * qv1[j];
        }
      }
    }
    {
      int beg = off_mv[pn], end = off_mv[pn + 1];
      int iters = (end - beg + 3) >> 2;
      for (int it = 0; it < iters; it++){
        int idx = beg + 4 * it + m4;
        bool valid = idx < end;
        int idc = valid ? idx : end - 1;
        uint2 pl = lmv[idc];             // (c|t<<16, m)
        unsigned c = pl.x & 0xffff, tix = pl.x >> 16;
        const uint4* trow = (const uint4*)(Ttb + (size_t)tix * 256);
        uint4 tp0 = trow[l16];
        uint4 tp1 = trow[l16 + 16];
        float2 sv = *(const float2*)(s3 + 2 * (size_t)pl.y);
        float2 rv = *(const float2*)(rz3 + 2 * (size_t)c);
        float4 qq = *(const float4*)(qkb + 4 * (size_t)pl.y);
        float q0 = g0 ? qq.y : qq.x;
        float q1 = g0 ? qq.w : qq.z;
        float pt0[8], pt1[8];
        unpk8(tp0, pt0); unpk8(tp1, pt1);
        float w0 = valid ? __expf(sv.x) * rv.x * q0 : 0.f;
        float w1 = valid ? __expf(sv.y) * rv.y * q1 : 0.f;
#pragma unroll
        for (int j = 0; j < 8; j++){
          acc[j]     += w0 * pt0[j];
          acc[8 + j] += w1 * pt1[j];
        }
      }
    }
#pragma unroll
    for (int j = 0; j < 16; j++){
      acc[j] += __shfl_xor(acc[j], 16, 64);
      acc[j] += __shfl_xor(acc[j], 32, 64);
    }
    const float cst = -0.5f / 64.0f;
    if (z < 16){
      uint4 o0, o1;
      o0.x = packbf(cst * acc[0], cst * acc[1]);
      o0.y = packbf(cst * acc[2], cst * acc[3]);
      o0.z = packbf(cst * acc[4], cst * acc[5]);
      o0.w = packbf(cst * acc[6], cst * acc[7]);
      o1.x = packbf(cst * acc[8], cst * acc[9]);
      o1.y = packbf(cst * acc[10], cst * acc[11]);
      o1.z = packbf(cst * acc[12], cst * acc[13]);
      o1.w = packbf(cst * acc[14], cst * acc[15]);
      uint4* dst = (uint4*)(dP + (size_t)n * F_TOT + 512);
      dst[l16] = o0;
      dst[l16 + 16] = o1;
    }
  }
}

// ================ PHASE F: bwd GEMM via MFMA (full 26 K-tiles) ================
__global__ __launch_bounds__(256) void k_bwd_mfma(const bf16* dP, const bf16* wfB, float* dG){
  int wave = threadIdx.x >> 6, lane = threadIdx.x & 63;
  int m0 = blockIdx.x * 64 + wave * 16;
  int rw = lane & 15, quad = lane >> 4;
  const bf16* aptr = dP + (size_t)(m0 + rw) * F_TOT + quad * 8;
  f32x4 acc[8];
#pragma unroll
  for (int i = 0; i < 8; i++) acc[i] = (f32x4){0.f, 0.f, 0.f, 0.f};
  for (int kt = 0; kt < 26; kt++){
    bf16x8 a = *(const bf16x8*)(aptr + kt * 32);
#pragma unroll
    for (int td = 0; td < 8; td++){
      bf16x8 b = *(const bf16x8*)(wfB + (((size_t)td * 26 + kt) * 64 + lane) * 8);
      acc[td] = __builtin_amdgcn_mfma_f32_16x16x32_bf16(a, b, acc[td], 0, 0, 0);
    }
  }
#pragma unroll
  for (int td = 0; td < 8; td++){
    int col = td * 16 + rw;
#pragma unroll
    for (int r = 0; r < 4; r++){
      int row = m0 + quad * 4 + r;
      dG[(size_t)row * 128 + col] = acc[td][r];
    }
  }
}

// ================ PHASE G: finalize (wave/node) + Eg write ================
__global__ __launch_bounds__(256) void k_finalize(const float* X, const float* dG, const float* gamma,
                    const float* mu, const float* rstd, const float* step_p,
                    const float* Eg, float* out){
  int wave = threadIdx.x >> 6, l = threadIdx.x & 63;
  int n = blockIdx.x * 4 + wave;
  float2 x2 = ((const float2*)(X + (size_t)n * 128))[l];
  float2 dg2 = ((const float2*)(dG + (size_t)n * 128))[l];
  float2 gg = ((const float2*)gamma)[l];
  float rs = rstd[n], m = mu[n];
  float xh0 = (x2.x - m) * rs, xh1 = (x2.y - m) * rs;
  float dxh0 = dg2.x * gg.x, dxh1 = dg2.y * gg.y;
  float s1 = wsum64(dxh0 + dxh1);
  float s2v = wsum64(dxh0 * xh0 + dxh1 * xh1);
  float g0 = x2.x + rs * (dxh0 - s1 * (1.0f / 128) - xh0 * (s2v * (1.0f / 128)));
  float g1 = x2.y + rs * (dxh1 - s1 * (1.0f / 128) - xh1 * (s2v * (1.0f / 128)));
  float gn = sqrtf(wsum64(g0 * g0 + g1 * g1));
  float gc = 1.0f / fmaxf(gn, 1.0f);
  g0 *= gc; g1 *= gc;
  float step = step_p[0];
  float xn0 = x2.x - step * g0, xn1 = x2.y - step * g1;
  float sn = sqrtf(wsum64(xn0 * xn0 + xn1 * xn1));
  float sc = 10.0f / fmaxf(sn, 10.0f);
  ((float2*)(out + (size_t)n * 128))[l] = make_float2(xn0 * sc, xn1 * sc);
  if (blockIdx.x == 0 && threadIdx.x < NG_G)
    out[(size_t)N_NODES * 128 + threadIdx.x] = Eg[threadIdx.x];
}

extern "C" void kernel_launch(void* const* d_in, const int* in_sizes, int n_in,
                              void* d_out, int out_size, void* d_ws, size_t ws_size,
                              hipStream_t stream) {
  const float* X     = (const float*)d_in[0];
  const int*  c_2    = (const int*) d_in[1];
  const int*  u_2    = (const int*) d_in[2];
  const int*  c_3    = (const int*) d_in[3];
  const int*  u_3    = (const int*) d_in[4];
  const int*  v_3    = (const int*) d_in[5];
  const int*  t_tau  = (const int*) d_in[6];
  const int*  batch  = (const int*) d_in[7];
  const float* a_2   = (const float*)d_in[8];
  const float* step_s= (const float*)d_in[9];
  const float* ln_g  = (const float*)d_in[10];
  const float* ln_b  = (const float*)d_in[11];
  const float* W_Q2  = (const float*)d_in[12];
  const float* W_K2  = (const float*)d_in[13];
  const float* W_Q3  = (const float*)d_in[14];
  const float* W_K3  = (const float*)d_in[15];
  const float* T_tau = (const float*)d_in[16];
  const float* W_Qm  = (const float*)d_in[17];
  const float* W_Km  = (const float*)d_in[18];
  const float* B_mem = (const float*)d_in[19];
  float* out = (float*)d_out;

  char* wb = (char*)d_ws;
  float* Wcat   = (float*)wb; wb += 768 * D_DIM * 4;
  float* Mprod  = (float*)wb; wb += 8192 * 4;
  float* mu     = (float*)wb; wb += N_NODES * 4;
  float* rstd   = (float*)wb; wb += N_NODES * 4;
  float* s2     = (float*)wb; wb += (size_t)E_EDG * 2 * 4;
  float* rz2    = (float*)wb; wb += N_NODES * 2 * 4;
  float* s3     = (float*)wb; wb += (size_t)M_MOT * 2 * 4;
  float* qkb    = (float*)wb; wb += (size_t)M_MOT * 4 * 4;
  float* tvb    = (float*)wb; wb += (size_t)M_MOT * 4 * 4;
  float* rz3    = (float*)wb; wb += N_NODES * 2 * 4;
  float* e_node = (float*)wb; wb += N_NODES * 4;
  float* e_pair = (float*)wb; wb += N_NODES * 4;
  float* e_mot  = (float*)wb; wb += N_NODES * 4;
  float* e_mem  = (float*)wb; wb += N_NODES * 4;
  float* Eg     = (float*)wb; wb += NG_G * 4;
  float* dG     = (float*)wb; wb += (size_t)N_NODES * D_DIM * 4;
  float* TV4    = (float*)wb; wb += (size_t)N_NODES * 32 * 4 * 4;  // 16.8MB
  bf16* Gb      = (bf16*)wb;  wb += (size_t)N_NODES * D_DIM * 2;
  bf16* P       = (bf16*)wb;  wb += (size_t)N_NODES * F_TOT * 2;
  bf16* dP      = (bf16*)wb;  wb += (size_t)N_NODES * F_TOT * 2;
  bf16* wfF     = (bf16*)wb;  wb += 106496 * 2;
  bf16* wfB     = (bf16*)wb;  wb += 106496 * 2;
  bf16* Ttb     = (bf16*)wb;  wb += 8192 * 2;
  int* cntcur   = (int*)wb;   wb += 8 * 5 * N_NODES * 4;   // 8 per-XCD copies
  int* off      = (int*)wb;   wb += 5 * (N_NODES + 1) * 4;
  wb = (char*)(((size_t)wb + 15) & ~(size_t)15);
  uint2* lec    = (uint2*)wb; wb += (size_t)E_EDG * 8;
  uint2* leu    = (uint2*)wb; wb += (size_t)E_EDG * 8;
  uint2* lmc    = (uint2*)wb; wb += (size_t)M_MOT * 8;
  uint2* lmu    = (uint2*)wb; wb += (size_t)M_MOT * 8;
  uint2* lmv    = (uint2*)wb; wb += (size_t)M_MOT * 8;

  const int* off_ec = off;
  const int* off_eu = off + (N_NODES + 1);
  const int* off_mc = off + 2 * (N_NODES + 1);
  const int* off_mu = off + 3 * (N_NODES + 1);
  const int* off_mv = off + 4 * (N_NODES + 1);

  hipMemsetAsync(cntcur, 0, (size_t)8 * 5 * N_NODES * sizeof(int), stream);
  hipMemsetAsync(Eg, 0, NG_G * sizeof(float), stream);
  hipLaunchKernelGGL(k_phaseA, dim3(1504), dim3(256), 0, stream,
                     c_2, u_2, c_3, u_3, v_3, W_Q2, W_K2, W_Q3, W_K3,
                     W_Qm, W_Km, B_mem, T_tau, cntcur, Wcat, Ttb, Mprod);
  hipLaunchKernelGGL(k_reduce8, dim3(160), dim3(256), 0, stream, cntcur);
  hipLaunchKernelGGL(k_phaseB, dim3(2157), dim3(1024), 0, stream,
                     cntcur, off, X, ln_g, ln_b, Gb, mu, rstd, e_node,
                     Wcat, Mprod, wfF, wfB);
  hipLaunchKernelGGL(k_fill, dim3(8192), dim3(256), 0, stream,
                     c_2, u_2, c_3, u_3, v_3, t_tau, cntcur,
                     lec, leu, lmc, lmu, lmv);
  hipLaunchKernelGGL(k_phaseC_gemm, dim3(6656), dim3(256), 0, stream,
                     Gb, wfF, P);
  hipLaunchKernelGGL(k_tv, dim3(512), dim3(256), 0, stream, P, Ttb, TV4);
  hipLaunchKernelGGL(k_fused_c, dim3(3 * (N_NODES / 4)), dim3(256), 0, stream,
                     P, lec, lmc, Ttb, TV4, a_2, off_ec, off_mc,
                     s2, rz2, s3, qkb, tvb, rz3, dP, e_pair, e_mot, e_mem);
  hipLaunchKernelGGL(k_phaseE, dim3(128 + 2 * (N_NODES / 4)), dim3(256), 0, stream,
                     P, leu, lmu, lmv, Ttb, s2, rz2, s3, rz3, qkb, tvb,
                     off_eu, off_mu, off_mv, dP,
                     e_node, e_pair, e_mot, e_mem, batch, Eg);
  hipLaunchKernelGGL(k_bwd_mfma, dim3(N_NODES / 64), dim3(256), 0, stream, dP, wfB, dG);
  hipLaunchKernelGGL(k_finalize, dim3(N_NODES / 4), dim3(256), 0, stream,
                     X, dG, ln_g, mu, rstd, step_s, Eg, out);
}

// Round 10
// 369.468 us; speedup vs baseline: 1.1601x; 1.0586x over previous
//
#include <hip/hip_runtime.h>
#include <hip/hip_bf16.h>
#include <math.h>

typedef __hip_bfloat16 bf16;
typedef short bf16x8 __attribute__((ext_vector_type(8)));
typedef float f32x4 __attribute__((ext_vector_type(4)));

#define N_NODES 32768
#define D_DIM 128
#define E_EDG 262144
#define M_MOT 131072
#define NG_G 32
#define F_TOT 832
// P: Q2[0,128) K2[128,256) Q3[256,512) K3[512,768) S_mem[768,832)
// dP: dQ2 dK2 dQ3 dK3 Pm ; -0.125*Km@W_Qm folded into bwd B-frags
// lam2=1 lam3=0.5 lamm=1 b2=b3=bm=1 ; no-max softmax, z as reciprocal
// R14: phaseC P-store via LDS tile (kept).
// R15: XCD-local fill scatter, interleaved with gemm in phaseC (kept --
//      R22 showed the interleave IS the overlap; separating regressed 16us).
// R16: wide phaseE (kept). R17: k_reduce8 + int4 scan (kept).
// R18: narrow fused_c (kept). R19: __expf/__logf (kept).
// R20 TV precompute: REVERTED (net -4.3us: fused_c -4 but k_tv +8).
// R21 NT hints: REVERTED (gfx950 NT = write-through; phaseC 55.6->85.5us).
// R22 stream split: REVERTED (serialized what the interleave overlapped).
// R23: pure revert to best-measured configuration (R6, 370.5us).

__device__ __forceinline__ int pidx(int n){ return ((n & 7) << 12) | (n >> 3); }

__device__ __forceinline__ float wsum64(float v){
#pragma unroll
  for (int o = 32; o > 0; o >>= 1) v += __shfl_xor(v, o, 64);
  return v;
}
__device__ __forceinline__ float hsum32(float v){
#pragma unroll
  for (int o = 16; o > 0; o >>= 1) v += __shfl_xor(v, o, 64);
  return v;
}
__device__ __forceinline__ float hmax32(float v){
#pragma unroll
  for (int o = 16; o > 0; o >>= 1) v = fmaxf(v, __shfl_xor(v, o, 64));
  return v;
}
__device__ __forceinline__ float hsum8(float v){
#pragma unroll
  for (int o = 4; o > 0; o >>= 1) v += __shfl_xor(v, o, 64);
  return v;
}
__device__ __forceinline__ float bflo(unsigned u){ return __uint_as_float(u << 16); }
__device__ __forceinline__ float bfhi(unsigned u){ return __uint_as_float(u & 0xffff0000u); }
__device__ __forceinline__ unsigned packbf(float x, float y){
  bf16 a = __float2bfloat16(x), b = __float2bfloat16(y);
  unsigned short ua = *(unsigned short*)&a, ub = *(unsigned short*)&b;
  return (unsigned)ua | ((unsigned)ub << 16);
}
__device__ __forceinline__ void unpk8(uint4 p, float* f){
  f[0] = bflo(p.x); f[1] = bfhi(p.x); f[2] = bflo(p.y); f[3] = bfhi(p.y);
  f[4] = bflo(p.z); f[5] = bfhi(p.z); f[6] = bflo(p.w); f[7] = bfhi(p.w);
}

// ================ PHASE A: hist (per-XCD copies) | Wcat/Ttb prep | Mprod ================
__global__ __launch_bounds__(256) void k_phaseA(
    const int* c2, const int* u2, const int* c3, const int* u3, const int* v3,
    const float* wq2, const float* wk2, const float* wq3, const float* wk3,
    const float* wqm, const float* wkm, const float* bmem, const float* Ttau,
    int* cnt, float* Wcat, bf16* Ttb, float* Mprod){
  __shared__ float KmL[64];
  int b = blockIdx.x, t = threadIdx.x;
  if (b < 1024){
    int* base = cnt + (size_t)(b & 7) * 5 * N_NODES;   // per-XCD private copy
    int i = b * 256 + t;
    atomicAdd(&base[pidx(c2[i])], 1);
    atomicAdd(&base[N_NODES + pidx(u2[i])], 1);
    if (i < M_MOT){
      atomicAdd(&base[2 * N_NODES + pidx(c3[i])], 1);
      atomicAdd(&base[3 * N_NODES + pidx(u3[i])], 1);
      atomicAdd(&base[4 * N_NODES + pidx(v3[i])], 1);
    }
  } else if (b < 1440){
    int idx = (b - 1024) * 256 + t;
    if (idx < 768 * D_DIM){
      int f = idx / D_DIM, d = idx - f * D_DIM;
      const float* src; int fr;
      if      (f < 128){ src = wq2; fr = f; }
      else if (f < 256){ src = wk2; fr = f - 128; }
      else if (f < 512){ src = wq3; fr = f - 256; }
      else             { src = wk3; fr = f - 512; }
      Wcat[f * D_DIM + d] = src[fr * D_DIM + d];
    } else {
      int j = idx - 768 * D_DIM; // < 8192
      Ttb[j] = __float2bfloat16(Ttau[j]);
    }
  } else {
    int hk = b - 1440;            // 0..63
    int h = hk >> 5, k = hk & 31;
    if (t < 64){
      const float* wrow = wkm + (size_t)(h * 64 + t) * D_DIM;
      const float* brow = bmem + k * D_DIM;
      float acc = 0.f;
      for (int d = 0; d < D_DIM; d++) acc += wrow[d] * brow[d];
      KmL[t] = acc;
    }
    __syncthreads();
    if (t < 128){
      const float* w = wqm + (size_t)(h * 64) * 128 + t;
      float acc = 0.f;
      for (int z = 0; z < 64; z++) acc += w[z * 128] * KmL[z];
      Mprod[t * 64 + hk] = acc;
    }
  }
}

// ================ REDUCE8: sum 8 hist copies into copy 0 (int4, 160 blocks) ================
__global__ __launch_bounds__(256) void k_reduce8(int* cnt){
  int idx = blockIdx.x * 256 + threadIdx.x;     // over 5*N/4 = 40960 int4s
  int4* base = (int4*)cnt;
  int4 s = base[idx];
#pragma unroll
  for (int rr = 1; rr < 8; rr++){
    int4 v = *(const int4*)(cnt + (size_t)rr * 5 * N_NODES + 4 * (size_t)idx);
    s.x += v.x; s.y += v.y; s.z += v.z; s.w += v.w;
  }
  base[idx] = s;
}

// ================ PHASE B: scan (copy 0, int4) | layernorm | pack_frags ================
__global__ __launch_bounds__(1024) void k_phaseB(
    int* cntcur, int* off,
    const float* X, const float* gamma, const float* beta,
    bf16* Gb, float* mu, float* rstd, float* e_node,
    const float* Wcat, const float* Mprod, bf16* wfF, bf16* wfB){
  __shared__ int sd[1024];
  int b = blockIdx.x, t = threadIdx.x;
  if (b < 5){
    int* c = cntcur + b * N_NODES;
    int* o = off + b * (N_NODES + 1);
    int4 lv[8];
    const int4* c4 = (const int4*)c;
#pragma unroll
    for (int j4 = 0; j4 < 8; j4++) lv[j4] = c4[t * 8 + j4];
    int* lvp = (int*)lv;
    int loc[32];
    int sum = 0;
#pragma unroll
    for (int j = 0; j < 32; j++){ loc[j] = sum; sum += lvp[j]; }
    sd[t] = sum;
    __syncthreads();
    for (int s = 1; s < 1024; s <<= 1){
      int v = (t >= s) ? sd[t - s] : 0;
      __syncthreads();
      sd[t] += v;
      __syncthreads();
    }
    int excl = sd[t] - sum;
#pragma unroll
    for (int j = 0; j < 32; j++){
      int val = excl + loc[j];
      o[t * 32 + j] = val;
      c[t * 32 + j] = val;         // copy 0 becomes "cur" for the fill
    }
    if (t == 1023) o[N_NODES] = sd[1023];
  } else if (b < 2053){
    int wv = t >> 6, l = t & 63;
    int n = (b - 5) * 16 + wv;
    float2 x2 = ((const float2*)(X + (size_t)n * 128))[l];
    float sumx = wsum64(x2.x + x2.y);
    float sumxx = wsum64(x2.x * x2.x + x2.y * x2.y);
    float m = sumx * (1.0f / 128.0f);
    float var = sumxx * (1.0f / 128.0f) - m * m;
    float rs = rsqrtf(var + 1e-5f);
    float2 gg = ((const float2*)gamma)[l];
    float2 bb = ((const float2*)beta)[l];
    ((unsigned*)(Gb + (size_t)n * 128))[l] =
        packbf(gg.x * (x2.x - m) * rs + bb.x, gg.y * (x2.y - m) * rs + bb.y);
    if (l == 0){ mu[n] = m; rstd[n] = rs; e_node[n] = 0.5f * sumxx; }
  } else {
    int idx = (b - 2053) * 1024 + t;   // < 106496
    int j = idx & 7, lane = (idx >> 3) & 63, tt = idx >> 9;
    {
      int tn = tt >> 2, kt = tt & 3;
      int f = tn * 16 + (lane & 15), d = kt * 32 + (lane >> 4) * 8 + j;
      float v = (f < 768) ? Wcat[f * 128 + d] : 0.125f * Mprod[d * 64 + (f - 768)];
      wfF[idx] = __float2bfloat16(v);
    }
    {
      int td = tt / 26, tf = tt - td * 26;
      int f = tf * 32 + (lane >> 4) * 8 + j, d = td * 16 + (lane & 15);
      float v = (f < 768) ? Wcat[f * 128 + d] : -0.125f * Mprod[d * 64 + (f - 768)];
      wfB[idx] = __float2bfloat16(v);
    }
  }
}

// ================ PHASE C: fwd_mfma (13/29) | fill (16/29, residue-owned) ================
__global__ __launch_bounds__(256) void k_phaseC(
    const bf16* Gb, const bf16* wfF, bf16* P,
    const int* c2, const int* u2, const int* c3, const int* u3, const int* v3,
    const int* t3, int* cur,
    uint2* lec, uint2* leu, uint2* lmc, uint2* lmu, uint2* lmv){
  int b = blockIdx.x;
  int g = b / 29, r = b - g * 29;
  if (r < 13){
    // 64x64 output tile, LDS-staged for sector-aligned coalesced stores.
    __shared__ unsigned shP[64 * 36];
    int f = g * 13 + r;
    int bx = f & 511, by = f >> 9;
    int wave = threadIdx.x >> 6, lane = threadIdx.x & 63;
    int m0 = bx * 64 + wave * 16;
    int tn0 = by * 4;
    int rw = lane & 15, quad = lane >> 4;
    const bf16* aptr = Gb + (size_t)(m0 + rw) * 128 + quad * 8;
    bf16x8 a[4];
#pragma unroll
    for (int kt = 0; kt < 4; kt++) a[kt] = *(const bf16x8*)(aptr + kt * 32);
    f32x4 acc[4];
#pragma unroll
    for (int i = 0; i < 4; i++) acc[i] = (f32x4){0.f, 0.f, 0.f, 0.f};
#pragma unroll
    for (int nf = 0; nf < 4; nf++){
      int tn = tn0 + nf;
#pragma unroll
      for (int kt = 0; kt < 4; kt++){
        bf16x8 bb = *(const bf16x8*)(wfF + (((size_t)tn * 4 + kt) * 64 + lane) * 8);
        acc[nf] = __builtin_amdgcn_mfma_f32_16x16x32_bf16(bb, a[kt], acc[nf], 0, 0, 0);
      }
    }
    int lrow = wave * 16 + rw;
#pragma unroll
    for (int nf = 0; nf < 4; nf++){
      unsigned lo = packbf(acc[nf][0], acc[nf][1]);
      unsigned hi = packbf(acc[nf][2], acc[nf][3]);
      *(uint2*)&shP[lrow * 36 + nf * 8 + quad * 2] = make_uint2(lo, hi);
    }
    __syncthreads();
    int t = threadIdx.x;
    int orow = t >> 2, s = t & 3;
    uint4 v0 = *(const uint4*)&shP[orow * 36 + s * 4];
    uint4 v1 = *(const uint4*)&shP[orow * 36 + 16 + s * 4];
    uint4* prow = (uint4*)(P + (size_t)(bx * 64 + orow) * F_TOT) + tn0 * 2 + s;
    prow[0] = v0;
    prow[4] = v1;
  } else {
    int j = g * 16 + (r - 13);     // 0..8191 ; 8 consecutive blocks per range
    int range = j >> 3;
    int res = b & 7;               // residue ownership == XCD under round-robin
    int i = range * 256 + threadIdx.x;
    {
      int c = c2[i], u = u2[i];
      if ((c & 7) == res){
        int pos = atomicAdd(&cur[pidx(c)], 1);
        lec[pos] = make_uint2((unsigned)u, (unsigned)i);
      }
      if ((u & 7) == res){
        int pos = atomicAdd(&cur[N_NODES + pidx(u)], 1);
        leu[pos] = make_uint2((unsigned)c, (unsigned)i);
      }
    }
    if (i < M_MOT){
      int c = c3[i], u = u3[i], v = v3[i], mt = t3[i];
      if ((c & 7) == res){
        int pos = atomicAdd(&cur[2 * N_NODES + pidx(c)], 1);
        lmc[pos] = make_uint2((unsigned)(u | (v << 16)), (unsigned)(mt | (i << 5)));
      }
      if ((u & 7) == res){
        int pos = atomicAdd(&cur[3 * N_NODES + pidx(u)], 1);
        lmu[pos] = make_uint2((unsigned)c, (unsigned)i);
      }
      if ((v & 7) == res){
        int pos = atomicAdd(&cur[4 * N_NODES + pidx(v)], 1);
        lmv[pos] = make_uint2((unsigned)(c | (mt << 16)), (unsigned)i);
      }
    }
  }
}

// ================ PHASE D: fused forward gathers (narrow, heads across lanes) ================
__global__ __launch_bounds__(256) void k_fused_c(const bf16* P, const uint2* lec, const uint2* lmc,
                   const bf16* Ttb, const float* a2, const int* off_ec, const int* off_mc,
                   float* s2, float* rz2, float* s3, float* qkb, float* tvb, float* rz3,
                   bf16* dP, float* e_pair, float* e_mot, float* e_mem){
  int b = blockIdx.x;
  int type = b % 3, grp = b / 3;
  int wave = threadIdx.x >> 6, z = threadIdx.x & 63;
  int n = grp * 4 + wave;
  int l = z & 31, lh = z >> 5;
  int pn = pidx(n);

  if (type == 0){
    // ---- edges: 4 per wave (16-lane groups), 8-lane head sub-groups ----
    int q = z >> 4, l16 = z & 15, hg = l16 >> 3;
    int beg = off_ec[pn], end = off_ec[pn + 1];
    uint4 qp = ((const uint4*)(P + (size_t)n * F_TOT))[l16];
    float qv[8]; unpk8(qp, qv);
    float acc[8] = {0,0,0,0,0,0,0,0};
    float zz = 0.f;
    int iters = (end - beg + 3) >> 2;
    for (int it = 0; it < iters; it++){
      int idx = beg + 4 * it + q;
      bool valid = idx < end;
      int idc = valid ? idx : end - 1;
      uint2 pl = lec[idc];               // (u, eid)
      float2 av = *(const float2*)(a2 + (size_t)pl.y * 2);
      uint4 kp = ((const uint4*)(P + (size_t)pl.x * F_TOT + 128))[l16];
      float kv[8]; unpk8(kp, kv);
      float d = 0.f;
#pragma unroll
      for (int j = 0; j < 8; j++) d += qv[j] * kv[j];
      float s = hsum8(d) * 0.125f + (hg ? av.y : av.x);
      if (valid && (l16 & 7) == 0) s2[2 * pl.y + hg] = s;
      float ex = valid ? __expf(s) : 0.f;
#pragma unroll
      for (int j = 0; j < 8; j++) acc[j] += ex * kv[j];
      zz += ex;
    }
#pragma unroll
    for (int j = 0; j < 8; j++){
      acc[j] += __shfl_xor(acc[j], 16, 64);
      acc[j] += __shfl_xor(acc[j], 32, 64);
    }
    zz += __shfl_xor(zz, 16, 64);
    zz += __shfl_xor(zz, 32, 64);
    float rz = (zz > 0.f) ? 1.0f / zz : 0.f;
    float coef = -0.125f * rz;
    if (z < 16){
      uint4 o;
      o.x = packbf(coef * acc[0], coef * acc[1]);
      o.y = packbf(coef * acc[2], coef * acc[3]);
      o.z = packbf(coef * acc[4], coef * acc[5]);
      o.w = packbf(coef * acc[6], coef * acc[7]);
      ((uint4*)(dP + (size_t)n * F_TOT))[l16] = o;
      if ((l16 & 7) == 0) rz2[n * 2 + hg] = rz;
    }
    float eterm = (zz > 0.f) ? -__logf(zz) : 0.f;   // lam2 = 1
    float eo = __shfl(eterm, 8, 64);
    if (z == 0) e_pair[n] = eterm + eo;
  } else if (type == 1){
    // ---- motifs: 2 per wave (32-lane halves), 8-lane hr groups ----
    int g = l >> 3, hg = g >> 1;
    int beg = off_mc[pn], end = off_mc[pn + 1];
    uint4 qp = ((const uint4*)(P + (size_t)n * F_TOT + 256))[l];
    float qv[8]; unpk8(qp, qv);
    float acc[8] = {0,0,0,0,0,0,0,0};
    float zz = 0.f;
    int iters = (end - beg + 1) >> 1;
    for (int it = 0; it < iters; it++){
      int idx = beg + 2 * it + lh;
      bool valid = idx < end;
      int idc = valid ? idx : end - 1;
      uint2 pl = lmc[idc];               // (u|v<<16, t|m<<5)
      int u = pl.x & 0xffff, v = pl.x >> 16;
      int tix = pl.y & 31; unsigned m = pl.y >> 5;
      uint4 kup = ((const uint4*)(P + (size_t)u * F_TOT + 512))[l];
      uint4 kvp = ((const uint4*)(P + (size_t)v * F_TOT + 512))[l];
      uint4 tp  = ((const uint4*)(Ttb + (size_t)tix * 256))[l];
      float k[8], vv[8], pt[8];
      unpk8(kup, k); unpk8(kvp, vv); unpk8(tp, pt);
      float dq = 0.f, dt = 0.f;
#pragma unroll
      for (int j = 0; j < 8; j++){ dq += qv[j] * k[j]; dt += pt[j] * vv[j]; }
      float qk = hsum8(dq);
      float tv = hsum8(dt);
      if (valid && (l & 7) == 0){ qkb[(size_t)4 * m + g] = qk; tvb[(size_t)4 * m + g] = tv; }
      float w = qk * tv;
      float s = (w + __shfl_xor(w, 8, 64)) * (1.0f / 64.0f);
      if (valid && (l & 15) == 0) s3[2 * m + hg] = s;
      float ex = valid ? __expf(s) : 0.f;
      float et = ex * tv;
#pragma unroll
      for (int j = 0; j < 8; j++) acc[j] += et * k[j];
      zz += ex;
    }
#pragma unroll
    for (int j = 0; j < 8; j++) acc[j] += __shfl_xor(acc[j], 32, 64);
    zz += __shfl_xor(zz, 32, 64);
    float rz = (zz > 0.f) ? 1.0f / zz : 0.f;
    float coef = (-0.5f / 64.0f) * rz;
    if (z < 32){
      uint4 o;
      o.x = packbf(coef * acc[0], coef * acc[1]);
      o.y = packbf(coef * acc[2], coef * acc[3]);
      o.z = packbf(coef * acc[4], coef * acc[5]);
      o.w = packbf(coef * acc[6], coef * acc[7]);
      ((uint4*)(dP + (size_t)n * F_TOT + 256))[l] = o;
      if ((l & 15) == 0) rz3[n * 2 + hg] = rz;
    }
    float eterm = (zz > 0.f) ? -0.5f * __logf(zz) : 0.f;   // lam3 = 0.5
    float eo = __shfl(eterm, 16, 64);
    if (z == 0) e_mot[n] = eterm + eo;
  } else {
    unsigned short us = ((const unsigned short*)(P + (size_t)n * F_TOT + 768))[z];
    float s = __uint_as_float((unsigned)us << 16);
    float mx = hmax32(s);
    float ex = __expf(s - mx);
    float se = hsum32(ex);
    float p = ex / se;
    bf16 pb = __float2bfloat16(p);
    ((unsigned short*)(dP + (size_t)n * F_TOT + 768))[z] = *(unsigned short*)&pb;
    float eterm = -(mx + __logf(se));
    float eo = __shfl(eterm, z ^ 32, 64);
    if (z == 0) e_mem[n] = eterm + eo;   // lamm=1, bm=1
  }
}

// ================ PHASE E: node_energy (128) | fused_uv (wide) ================
__global__ __launch_bounds__(256) void k_phaseE(const bf16* P, const uint2* leu,
                    const uint2* lmu, const uint2* lmv, const bf16* Ttb,
                    const float* s2, const float* rz2, const float* s3, const float* rz3,
                    const float* qkb, const float* tvb,
                    const int* off_eu, const int* off_mu, const int* off_mv, bf16* dP,
                    const float* e_node, const float* e_pair, const float* e_mot,
                    const float* e_mem, const int* batch, float* Eg){
  __shared__ float eg[NG_G];
  int b = blockIdx.x;
  if (b < 128){
    int t = threadIdx.x;
    if (t < NG_G) eg[t] = 0.f;
    __syncthreads();
    int n = b * 256 + t;
    float e = e_node[n] + e_pair[n] + e_mot[n] + e_mem[n];
    atomicAdd(&eg[batch[n]], e);
    __syncthreads();
    if (t < NG_G) atomicAdd(&Eg[t], eg[t]);
    return;
  }
  int b2 = b - 128;
  int type = b2 & 1, grp = b2 >> 1;
  int wave = threadIdx.x >> 6, z = threadIdx.x & 63;
  int n = grp * 4 + wave;
  int pn = pidx(n);

  if (type == 0){
    // dK2[u]: 8 edges per wave-iter, 8 lanes x 32B per edge
    int e8 = z >> 3, l8 = z & 7;
    int beg = off_eu[pn], end = off_eu[pn + 1];
    float acc[16];
#pragma unroll
    for (int j = 0; j < 16; j++) acc[j] = 0.f;
    int iters = (end - beg + 7) >> 3;
    for (int it = 0; it < iters; it++){
      int idx = beg + 8 * it + e8;
      bool valid = idx < end;
      int idc = valid ? idx : end - 1;
      uint2 pl = leu[idc];               // (c, eid)
      const uint4* qrow = (const uint4*)(P + (size_t)pl.x * F_TOT);
      uint4 qp0 = qrow[l8];
      uint4 qp1 = qrow[l8 + 8];
      float2 sv = *(const float2*)(s2 + 2 * (size_t)pl.y);
      float2 rv = *(const float2*)(rz2 + 2 * (size_t)pl.x);
      float qv0[8], qv1[8];
      unpk8(qp0, qv0); unpk8(qp1, qv1);
      float p0 = valid ? __expf(sv.x) * rv.x : 0.f;
      float p1 = valid ? __expf(sv.y) * rv.y : 0.f;
#pragma unroll
      for (int j = 0; j < 8; j++){
        acc[j]     += p0 * qv0[j];
        acc[8 + j] += p1 * qv1[j];
      }
    }
#pragma unroll
    for (int j = 0; j < 16; j++){
      acc[j] += __shfl_xor(acc[j], 8, 64);
      acc[j] += __shfl_xor(acc[j], 16, 64);
      acc[j] += __shfl_xor(acc[j], 32, 64);
    }
    if (z < 8){
      uint4 o0, o1;
      o0.x = packbf(-0.125f * acc[0], -0.125f * acc[1]);
      o0.y = packbf(-0.125f * acc[2], -0.125f * acc[3]);
      o0.z = packbf(-0.125f * acc[4], -0.125f * acc[5]);
      o0.w = packbf(-0.125f * acc[6], -0.125f * acc[7]);
      o1.x = packbf(-0.125f * acc[8], -0.125f * acc[9]);
      o1.y = packbf(-0.125f * acc[10], -0.125f * acc[11]);
      o1.z = packbf(-0.125f * acc[12], -0.125f * acc[13]);
      o1.w = packbf(-0.125f * acc[14], -0.125f * acc[15]);
      uint4* dst = (uint4*)(dP + (size_t)n * F_TOT + 128);
      dst[z] = o0;
      dst[z + 8] = o1;
    }
  } else {
    // dK3[n]: 4 motifs per wave-iter, 16 lanes x 32B per motif
    int m4 = z >> 4, l16 = z & 15;
    int g0 = l16 >> 3;                  // 0 or 1 (r index within head)
    float acc[16];
#pragma unroll
    for (int j = 0; j < 16; j++) acc[j] = 0.f;
    {
      int beg = off_mu[pn], end = off_mu[pn + 1];
      int iters = (end - beg + 3) >> 2;
      for (int it = 0; it < iters; it++){
        int idx = beg + 4 * it + m4;
        bool valid = idx < end;
        int idc = valid ? idx : end - 1;
        uint2 pl = lmu[idc];             // (c, m)
        const uint4* qrow = (const uint4*)(P + (size_t)pl.x * F_TOT + 256);
        uint4 qp0 = qrow[l16];
        uint4 qp1 = qrow[l16 + 16];
        float2 sv = *(const float2*)(s3 + 2 * (size_t)pl.y);
        float2 rv = *(const float2*)(rz3 + 2 * (size_t)pl.x);
        float4 tq = *(const float4*)(tvb + 4 * (size_t)pl.y);
        float t0 = g0 ? tq.y : tq.x;
        float t1 = g0 ? tq.w : tq.z;
        float qv0[8], qv1[8];
        unpk8(qp0, qv0); unpk8(qp1, qv1);
        float w0 = valid ? __expf(sv.x) * rv.x * t0 : 0.f;
        float w1 = valid ? __expf(sv.y) * rv.y * t1 : 0.f;
#pragma unroll
        for (int j = 0; j < 8; j++){
          acc[j]     += w0 * qv0[j];
          acc[8 + j] += w1 * qv1[j];
        }
      }
    }
    {
      int beg = off_mv[pn], end = off_mv[pn + 1];
      int iters = (end - beg + 3) >> 2;
      for (int it = 0; it < iters; it++){
        int idx = beg + 4 * it + m4;
        bool valid = idx < end;
        int idc = valid ? idx : end - 1;
        uint2 pl = lmv[idc];             // (c|t<<16, m)
        unsigned c = pl.x & 0xffff, tix = pl.x >> 16;
        const uint4* trow = (const uint4*)(Ttb + (size_t)tix * 256);
        uint4 tp0 = trow[l16];
        uint4 tp1 = trow[l16 + 16];
        float2 sv = *(const float2*)(s3 + 2 * (size_t)pl.y);
        float2 rv = *(const float2*)(rz3 + 2 * (size_t)c);
        float4 qq = *(const float4*)(qkb + 4 * (size_t)pl.y);
        float q0 = g0 ? qq.y : qq.x;
        float q1 = g0 ? qq.w : qq.z;
        float pt0[8], pt1[8];
        unpk8(tp0, pt0); unpk8(tp1, pt1);
        float w0 = valid ? __expf(sv.x) * rv.x * q0 : 0.f;
        float w1 = valid ? __expf(sv.y) * rv.y * q1 : 0.f;
#pragma unroll
        for (int j = 0; j < 8; j++){
          acc[j]     += w0 * pt0[j];
          acc[8 + j] += w1 * pt1[j];
        }
      }
    }
#pragma unroll
    for (int j = 0; j < 16; j++){
      acc[j] += __shfl_xor(acc[j], 16, 64);
      acc[j] += __shfl_xor(acc[j], 32, 64);
    }
    const float cst = -0.5f / 64.0f;
    if (z < 16){
      uint4 o0, o1;
      o0.x = packbf(cst * acc[0], cst * acc[1]);
      o0.y = packbf(cst * acc[2], cst * acc[3]);
      o0.z = packbf(cst * acc[4], cst * acc[5]);
      o0.w = packbf(cst * acc[6], cst * acc[7]);
      o1.x = packbf(cst * acc[8], cst * acc[9]);
      o1.y = packbf(cst * acc[10], cst * acc[11]);
      o1.z = packbf(cst * acc[12], cst * acc[13]);
      o1.w = packbf(cst * acc[14], cst * acc[15]);
      uint4* dst = (uint4*)(dP + (size_t)n * F_TOT + 512);
      dst[l16] = o0;
      dst[l16 + 16] = o1;
    }
  }
}

// ================ PHASE F: bwd GEMM via MFMA (full 26 K-tiles) ================
__global__ __launch_bounds__(256) void k_bwd_mfma(const bf16* dP, const bf16* wfB, float* dG){
  int wave = threadIdx.x >> 6, lane = threadIdx.x & 63;
  int m0 = blockIdx.x * 64 + wave * 16;
  int rw = lane & 15, quad = lane >> 4;
  const bf16* aptr = dP + (size_t)(m0 + rw) * F_TOT + quad * 8;
  f32x4 acc[8];
#pragma unroll
  for (int i = 0; i < 8; i++) acc[i] = (f32x4){0.f, 0.f, 0.f, 0.f};
  for (int kt = 0; kt < 26; kt++){
    bf16x8 a = *(const bf16x8*)(aptr + kt * 32);
#pragma unroll
    for (int td = 0; td < 8; td++){
      bf16x8 b = *(const bf16x8*)(wfB + (((size_t)td * 26 + kt) * 64 + lane) * 8);
      acc[td] = __builtin_amdgcn_mfma_f32_16x16x32_bf16(a, b, acc[td], 0, 0, 0);
    }
  }
#pragma unroll
  for (int td = 0; td < 8; td++){
    int col = td * 16 + rw;
#pragma unroll
    for (int r = 0; r < 4; r++){
      int row = m0 + quad * 4 + r;
      dG[(size_t)row * 128 + col] = acc[td][r];
    }
  }
}

// ================ PHASE G: finalize (wave/node) + Eg write ================
__global__ __launch_bounds__(256) void k_finalize(const float* X, const float* dG, const float* gamma,
                    const float* mu, const float* rstd, const float* step_p,
                    const float* Eg, float* out){
  int wave = threadIdx.x >> 6, l = threadIdx.x & 63;
  int n = blockIdx.x * 4 + wave;
  float2 x2 = ((const float2*)(X + (size_t)n * 128))[l];
  float2 dg2 = ((const float2*)(dG + (size_t)n * 128))[l];
  float2 gg = ((const float2*)gamma)[l];
  float rs = rstd[n], m = mu[n];
  float xh0 = (x2.x - m) * rs, xh1 = (x2.y - m) * rs;
  float dxh0 = dg2.x * gg.x, dxh1 = dg2.y * gg.y;
  float s1 = wsum64(dxh0 + dxh1);
  float s2v = wsum64(dxh0 * xh0 + dxh1 * xh1);
  float g0 = x2.x + rs * (dxh0 - s1 * (1.0f / 128) - xh0 * (s2v * (1.0f / 128)));
  float g1 = x2.y + rs * (dxh1 - s1 * (1.0f / 128) - xh1 * (s2v * (1.0f / 128)));
  float gn = sqrtf(wsum64(g0 * g0 + g1 * g1));
  float gc = 1.0f / fmaxf(gn, 1.0f);
  g0 *= gc; g1 *= gc;
  float step = step_p[0];
  float xn0 = x2.x - step * g0, xn1 = x2.y - step * g1;
  float sn = sqrtf(wsum64(xn0 * xn0 + xn1 * xn1));
  float sc = 10.0f / fmaxf(sn, 10.0f);
  ((float2*)(out + (size_t)n * 128))[l] = make_float2(xn0 * sc, xn1 * sc);
  if (blockIdx.x == 0 && threadIdx.x < NG_G)
    out[(size_t)N_NODES * 128 + threadIdx.x] = Eg[threadIdx.x];
}

extern "C" void kernel_launch(void* const* d_in, const int* in_sizes, int n_in,
                              void* d_out, int out_size, void* d_ws, size_t ws_size,
                              hipStream_t stream) {
  const float* X     = (const float*)d_in[0];
  const int*  c_2    = (const int*) d_in[1];
  const int*  u_2    = (const int*) d_in[2];
  const int*  c_3    = (const int*) d_in[3];
  const int*  u_3    = (const int*) d_in[4];
  const int*  v_3    = (const int*) d_in[5];
  const int*  t_tau  = (const int*) d_in[6];
  const int*  batch  = (const int*) d_in[7];
  const float* a_2   = (const float*)d_in[8];
  const float* step_s= (const float*)d_in[9];
  const float* ln_g  = (const float*)d_in[10];
  const float* ln_b  = (const float*)d_in[11];
  const float* W_Q2  = (const float*)d_in[12];
  const float* W_K2  = (const float*)d_in[13];
  const float* W_Q3  = (const float*)d_in[14];
  const float* W_K3  = (const float*)d_in[15];
  const float* T_tau = (const float*)d_in[16];
  const float* W_Qm  = (const float*)d_in[17];
  const float* W_Km  = (const float*)d_in[18];
  const float* B_mem = (const float*)d_in[19];
  float* out = (float*)d_out;

  char* wb = (char*)d_ws;
  float* Wcat   = (float*)wb; wb += 768 * D_DIM * 4;
  float* Mprod  = (float*)wb; wb += 8192 * 4;
  float* mu     = (float*)wb; wb += N_NODES * 4;
  float* rstd   = (float*)wb; wb += N_NODES * 4;
  float* s2     = (float*)wb; wb += (size_t)E_EDG * 2 * 4;
  float* rz2    = (float*)wb; wb += N_NODES * 2 * 4;
  float* s3     = (float*)wb; wb += (size_t)M_MOT * 2 * 4;
  float* qkb    = (float*)wb; wb += (size_t)M_MOT * 4 * 4;
  float* tvb    = (float*)wb; wb += (size_t)M_MOT * 4 * 4;
  float* rz3    = (float*)wb; wb += N_NODES * 2 * 4;
  float* e_node = (float*)wb; wb += N_NODES * 4;
  float* e_pair = (float*)wb; wb += N_NODES * 4;
  float* e_mot  = (float*)wb; wb += N_NODES * 4;
  float* e_mem  = (float*)wb; wb += N_NODES * 4;
  float* Eg     = (float*)wb; wb += NG_G * 4;
  float* dG     = (float*)wb; wb += (size_t)N_NODES * D_DIM * 4;
  bf16* Gb      = (bf16*)wb;  wb += (size_t)N_NODES * D_DIM * 2;
  bf16* P       = (bf16*)wb;  wb += (size_t)N_NODES * F_TOT * 2;
  bf16* dP      = (bf16*)wb;  wb += (size_t)N_NODES * F_TOT * 2;
  bf16* wfF     = (bf16*)wb;  wb += 106496 * 2;
  bf16* wfB     = (bf16*)wb;  wb += 106496 * 2;
  bf16* Ttb     = (bf16*)wb;  wb += 8192 * 2;
  int* cntcur   = (int*)wb;   wb += 8 * 5 * N_NODES * 4;   // 8 per-XCD copies
  int* off      = (int*)wb;   wb += 5 * (N_NODES + 1) * 4;
  wb = (char*)(((size_t)wb + 15) & ~(size_t)15);
  uint2* lec    = (uint2*)wb; wb += (size_t)E_EDG * 8;
  uint2* leu    = (uint2*)wb; wb += (size_t)E_EDG * 8;
  uint2* lmc    = (uint2*)wb; wb += (size_t)M_MOT * 8;
  uint2* lmu    = (uint2*)wb; wb += (size_t)M_MOT * 8;
  uint2* lmv    = (uint2*)wb; wb += (size_t)M_MOT * 8;

  const int* off_ec = off;
  const int* off_eu = off + (N_NODES + 1);
  const int* off_mc = off + 2 * (N_NODES + 1);
  const int* off_mu = off + 3 * (N_NODES + 1);
  const int* off_mv = off + 4 * (N_NODES + 1);

  hipMemsetAsync(cntcur, 0, (size_t)8 * 5 * N_NODES * sizeof(int), stream);
  hipMemsetAsync(Eg, 0, NG_G * sizeof(float), stream);
  hipLaunchKernelGGL(k_phaseA, dim3(1504), dim3(256), 0, stream,
                     c_2, u_2, c_3, u_3, v_3, W_Q2, W_K2, W_Q3, W_K3,
                     W_Qm, W_Km, B_mem, T_tau, cntcur, Wcat, Ttb, Mprod);
  hipLaunchKernelGGL(k_reduce8, dim3(160), dim3(256), 0, stream, cntcur);
  hipLaunchKernelGGL(k_phaseB, dim3(2157), dim3(1024), 0, stream,
                     cntcur, off, X, ln_g, ln_b, Gb, mu, rstd, e_node,
                     Wcat, Mprod, wfF, wfB);
  hipLaunchKernelGGL(k_phaseC, dim3(512 * 29), dim3(256), 0, stream,
                     Gb, wfF, P, c_2, u_2, c_3, u_3, v_3, t_tau, cntcur,
                     lec, leu, lmc, lmu, lmv);
  hipLaunchKernelGGL(k_fused_c, dim3(3 * (N_NODES / 4)), dim3(256), 0, stream,
                     P, lec, lmc, Ttb, a_2, off_ec, off_mc,
                     s2, rz2, s3, qkb, tvb, rz3, dP, e_pair, e_mot, e_mem);
  hipLaunchKernelGGL(k_phaseE, dim3(128 + 2 * (N_NODES / 4)), dim3(256), 0, stream,
                     P, leu, lmu, lmv, Ttb, s2, rz2, s3, rz3, qkb, tvb,
                     off_eu, off_mu, off_mv, dP,
                     e_node, e_pair, e_mot, e_mem, batch, Eg);
  hipLaunchKernelGGL(k_bwd_mfma, dim3(N_NODES / 64), dim3(256), 0, stream, dP, wfB, dG);
  hipLaunchKernelGGL(k_finalize, dim3(N_NODES / 4), dim3(256), 0, stream,
                     X, dG, ln_g, mu, rstd, step_s, Eg, out);
}